// Round 1
// baseline (652.712 us; speedup 1.0000x reference)
//
#include <hip/hip_runtime.h>
#include <cstdint>
#include <cstddef>

// SS2D: B=2, H=W=64 (L=4096), D_MODEL=96, D_INNER=192, K=4 dirs, N=16 states, DT_RANK=6.
// All fp32. Two-pass chunked selective scan (32 chunks x 128 steps).
// ws usage: ~96.2 MB.

#define LPOS 4096

__device__ __forceinline__ float siluf(float x){ return x * (1.f/(1.f+__expf(-x))); }

template<int NK4, int STR>
__device__ __forceinline__ void micro_mm(const float (&As)[64][STR], const float (&Bs)[64][STR],
                                         int tx, int ty, float (&acc)[4][4])
{
#pragma unroll
  for (int k4 = 0; k4 < NK4; k4++){
    float4 a[4], b[4];
#pragma unroll
    for (int i = 0; i < 4; i++) a[i] = *(const float4*)&As[ty*4+i][k4*4];
#pragma unroll
    for (int j = 0; j < 4; j++) b[j] = *(const float4*)&Bs[tx*4+j][k4*4];
#pragma unroll
    for (int i = 0; i < 4; i++)
#pragma unroll
      for (int j = 0; j < 4; j++){
        acc[i][j] = fmaf(a[i].x, b[j].x, acc[i][j]);
        acc[i][j] = fmaf(a[i].y, b[j].y, acc[i][j]);
        acc[i][j] = fmaf(a[i].z, b[j].z, acc[i][j]);
        acc[i][j] = fmaf(a[i].w, b[j].w, acc[i][j]);
      }
  }
}

// ---------------- Stage 1: xz = x @ W_in^T + b_in; split -> xx, silu(z) ----------------
// M=8192 (B*L), K=96, N=384. grid(128,6), block 256.
__global__ __launch_bounds__(256) void k_gemm_in(
    const float* __restrict__ x, const float* __restrict__ W,
    const float* __restrict__ bias, float* __restrict__ xx, float* __restrict__ zs)
{
  __shared__ float As[64][100];
  __shared__ float Bs[64][100];
  const int m0 = blockIdx.x*64, n0 = blockIdx.y*64;
  const int tid = threadIdx.x;
#pragma unroll
  for (int i = 0; i < 6; i++){
    int idx = tid + i*256;
    int r = idx/24, c4 = idx%24;
    *(float4*)&As[r][c4*4] = *(const float4*)(x + (size_t)(m0+r)*96 + c4*4);
    *(float4*)&Bs[r][c4*4] = *(const float4*)(W + (size_t)(n0+r)*96 + c4*4);
  }
  __syncthreads();
  const int tx = tid & 15, ty = tid >> 4;
  float acc[4][4] = {};
  micro_mm<24,100>(As, Bs, tx, ty, acc);
#pragma unroll
  for (int i = 0; i < 4; i++){
    int m = m0 + ty*4 + i;
#pragma unroll
    for (int j = 0; j < 4; j++){
      int n = n0 + tx*4 + j;
      float v = acc[i][j] + bias[n];
      if (n < 192) xx[(size_t)m*192 + n] = v;
      else         zs[(size_t)m*192 + (n-192)] = siluf(v);
    }
  }
}

// ---------------- Stage 2: depthwise 3x3 SAME conv + bias + silu; writes xc and spatial-transposed xcT ----------------
__global__ __launch_bounds__(256) void k_conv(
    const float* __restrict__ xx, const float* __restrict__ cw, const float* __restrict__ cb,
    float* __restrict__ xc, float* __restrict__ xcT)
{
  int gid = blockIdx.x*256 + threadIdx.x;
  int c = gid % 192;
  int l = (gid/192) & 4095;
  int b = gid / (192*4096);
  int h = l >> 6, w = l & 63;
  float s = 0.f;
#pragma unroll
  for (int kh = 0; kh < 3; kh++){
    int h2 = h + kh - 1;
    if ((unsigned)h2 >= 64u) continue;
#pragma unroll
    for (int kw = 0; kw < 3; kw++){
      int w2 = w + kw - 1;
      if ((unsigned)w2 >= 64u) continue;
      s += xx[((size_t)b*4096 + h2*64 + w2)*192 + c] * cw[c*9 + kh*3 + kw];
    }
  }
  s = siluf(s + cb[c]);
  xc[((size_t)b*4096 + l)*192 + c] = s;
  int tl = (l & 63)*64 + (l >> 6);
  xcT[((size_t)b*4096 + tl)*192 + c] = s;
}

// ---------------- Stage 3: x_dbl[b, p(152), l] = W_xp @ concat4(xc views) + b_xp ----------------
// K=768 in 8 chunks of 96 (chunk -> direction kp = kc/2). grid(64, 3, 2), block 256.
// Stored as x_dbl[b][k][l][38] (k = p/38).
__global__ __launch_bounds__(256) void k_gemm_xdbl(
    const float* __restrict__ xc, const float* __restrict__ xcT,
    const float* __restrict__ Wxp, const float* __restrict__ bxp,
    float* __restrict__ xdbl)
{
  __shared__ float As[64][100];
  __shared__ float Bs[64][100];
  const int m0 = blockIdx.x*64;       // l tile
  const int n0 = blockIdx.y*64;       // p tile
  const int b  = blockIdx.z;
  const int tid = threadIdx.x;
  const int tx = tid & 15, ty = tid >> 4;
  float acc[4][4] = {};
  for (int kc = 0; kc < 8; kc++){
    const int kp = kc >> 1, off = (kc & 1)*96;
    const float* src = (kp & 1) ? xcT : xc;
    const bool rev = (kp >= 2);
    __syncthreads();
#pragma unroll
    for (int i = 0; i < 6; i++){
      int idx = tid + i*256;
      int r = idx/24, c4 = idx%24;
      int l = m0 + r; int ls = rev ? 4095 - l : l;
      *(float4*)&As[r][c4*4] = *(const float4*)(src + ((size_t)b*4096 + ls)*192 + off + c4*4);
      int p = n0 + r;
      float4 wv = make_float4(0.f,0.f,0.f,0.f);
      if (p < 152) wv = *(const float4*)(Wxp + (size_t)p*768 + kp*192 + off + c4*4);
      *(float4*)&Bs[r][c4*4] = wv;
    }
    __syncthreads();
    micro_mm<24,100>(As, Bs, tx, ty, acc);
  }
#pragma unroll
  for (int i = 0; i < 4; i++){
    int l = m0 + ty*4 + i;
#pragma unroll
    for (int j = 0; j < 4; j++){
      int p = n0 + tx*4 + j;
      if (p < 152){
        int k = p/38, pp = p%38;
        xdbl[(((size_t)b*4 + k)*4096 + l)*38 + pp] = acc[i][j] + bxp[p];
      }
    }
  }
}

// ---------------- Stage 4: dt_eff = softplus(W_dt @ dts + b_dt + dt_bias) ----------------
// M=4096/b, N=768, K=24. grid(64, 12, 2). Stored dt_eff[b][k][l][192].
__global__ __launch_bounds__(256) void k_gemm_dt(
    const float* __restrict__ xdbl, const float* __restrict__ Wdt,
    const float* __restrict__ bdt, const float* __restrict__ dtbias,
    float* __restrict__ dte)
{
  __shared__ float As[64][28];
  __shared__ float Bs[64][28];
  const int m0 = blockIdx.x*64;
  const int n0 = blockIdx.y*64;
  const int b  = blockIdx.z;
  const int tid = threadIdx.x;
#pragma unroll
  for (int i = 0; i < 6; i++){
    int idx = tid + i*256;
    int r = idx/24, cc = idx%24;
    int kp = cc/6, ri = cc%6;
    As[r][cc] = xdbl[(((size_t)b*4 + kp)*4096 + (m0+r))*38 + ri];
    Bs[r][cc] = Wdt[(size_t)(n0+r)*24 + cc];
  }
  __syncthreads();
  const int tx = tid & 15, ty = tid >> 4;
  float acc[4][4] = {};
  micro_mm<6,28>(As, Bs, tx, ty, acc);
#pragma unroll
  for (int i = 0; i < 4; i++){
    int l = m0 + ty*4 + i;
#pragma unroll
    for (int j = 0; j < 4; j++){
      int c = n0 + tx*4 + j;
      float v = acc[i][j] + bdt[c] + dtbias[c];
      v = (v > 20.f) ? v : log1pf(__expf(v));
      dte[(((size_t)b*4 + c/192)*4096 + l)*192 + (c%192)] = v;
    }
  }
}

// ---------------- Selective scan, two-pass chunked ----------------
// wave = 64 lanes: lane = didx*16 + n; 4 channels/wave, 16 states/channel.
// wid = ((b*4+k)*48 + dg)*32 + chunk; 12288 wids, 4 waves/block -> 3072 blocks.
__global__ __launch_bounds__(256) void k_scanA(
    const float* __restrict__ xc, const float* __restrict__ xcT,
    const float* __restrict__ xdbl, const float* __restrict__ dte,
    const float* __restrict__ A_log,
    float* __restrict__ Pb, float* __restrict__ Sb)
{
  const int lane = threadIdx.x & 63;
  const int wid  = blockIdx.x*4 + (threadIdx.x >> 6);
  int tmp = wid;
  const int ck = tmp & 31; tmp >>= 5;
  const int dg = tmp % 48; tmp /= 48;
  const int k  = tmp & 3;
  const int b  = tmp >> 2;
  const int n = lane & 15, didx = lane >> 4;
  const int d = dg*4 + didx, ch = k*192 + d;
  const float An = -__expf(A_log[ch*16 + n]);
  const int l0 = ck*128;
  const float* srcb = (k & 1) ? xcT : xc;
  const bool rev = (k >= 2);
  const float* dtp = dte  + (((size_t)b*4 + k)*4096 + l0)*192 + d;
  const float* xdp = xdbl + (((size_t)b*4 + k)*4096 + l0)*38;
  const float* up  = srcb + ((size_t)b*4096 + (rev ? 4095 - l0 : l0))*192 + d;
  const int ustride = rev ? -192 : 192;
  float h = 0.f, P = 1.f;
  for (int t = 0; t < 128; t++){
    float dt = dtp[0];
    float u  = up[0];
    float Bv = xdp[6 + n];
    float dA = __expf(dt*An);
    h = dA*h + (dt*u)*Bv;
    P *= dA;
    dtp += 192; xdp += 38; up += ustride;
  }
  Pb[(size_t)wid*64 + lane] = P;
  Sb[(size_t)wid*64 + lane] = h;
}

__global__ __launch_bounds__(256) void k_scanB(
    const float* __restrict__ Pb, const float* __restrict__ Sb, float* __restrict__ H0)
{
  int sid = blockIdx.x*256 + threadIdx.x;   // 24576 states
  int lane = sid & 63; int rest = sid >> 6;
  int dg = rest % 48; rest /= 48;
  int k = rest & 3; int b = rest >> 2;
  size_t base = ((((size_t)b*4 + k)*48 + dg)*32)*64 + lane;
  float h = 0.f;
  for (int ck = 0; ck < 32; ck++){
    size_t idx = base + (size_t)ck*64;
    H0[idx] = h;
    h = Pb[idx]*h + Sb[idx];
  }
}

__global__ __launch_bounds__(256) void k_scanC(
    const float* __restrict__ xc, const float* __restrict__ xcT,
    const float* __restrict__ xdbl, const float* __restrict__ dte,
    const float* __restrict__ A_log, const float* __restrict__ Dskip,
    const float* __restrict__ H0, float* __restrict__ ys)
{
  const int lane = threadIdx.x & 63;
  const int wid  = blockIdx.x*4 + (threadIdx.x >> 6);
  int tmp = wid;
  const int ck = tmp & 31; tmp >>= 5;
  const int dg = tmp % 48; tmp /= 48;
  const int k  = tmp & 3;
  const int b  = tmp >> 2;
  const int n = lane & 15, didx = lane >> 4;
  const int d = dg*4 + didx, ch = k*192 + d;
  const float An = -__expf(A_log[ch*16 + n]);
  const float Dv = Dskip[ch];
  const int l0 = ck*128;
  const float* srcb = (k & 1) ? xcT : xc;
  const bool rev = (k >= 2);
  const float* dtp = dte  + (((size_t)b*4 + k)*4096 + l0)*192 + d;
  const float* xdp = xdbl + (((size_t)b*4 + k)*4096 + l0)*38;
  const float* up  = srcb + ((size_t)b*4096 + (rev ? 4095 - l0 : l0))*192 + d;
  const int ustride = rev ? -192 : 192;
  float h = H0[(size_t)wid*64 + lane];
  for (int t = 0; t < 128; t++){
    int l = l0 + t;
    float dt = dtp[0];
    float u  = up[0];
    float Bv = xdp[6 + n];
    float Cv = xdp[22 + n];
    float dA = __expf(dt*An);
    h = dA*h + (dt*u)*Bv;
    float p = h*Cv;
    p += __shfl_xor(p, 1);
    p += __shfl_xor(p, 2);
    p += __shfl_xor(p, 4);
    p += __shfl_xor(p, 8);
    if (n == 0){
      float y = p + u*Dv;
      int pos;
      if (k == 0)      pos = l;
      else if (k == 1) pos = (l & 63)*64 + (l >> 6);
      else { int l2 = 4095 - l; pos = (k == 2) ? l2 : ((l2 & 63)*64 + (l2 >> 6)); }
      ys[(((size_t)k*2 + b)*4096 + pos)*192 + d] = y;
    }
    dtp += 192; xdp += 38; up += ustride;
  }
}

// ---------------- Stage 6: merge 4 planes + LayerNorm(gamma,beta) * silu(z) ----------------
// One wave per row; 4 rows/block. grid 2048.
__global__ __launch_bounds__(256) void k_ln(
    const float* __restrict__ ys, const float* __restrict__ zs,
    const float* __restrict__ gamma, const float* __restrict__ beta,
    float* __restrict__ yln)
{
  int row = blockIdx.x*4 + (threadIdx.x >> 6);
  int lane = threadIdx.x & 63;
  int b = row >> 12; int l = row & 4095;
  float v[3];
#pragma unroll
  for (int j = 0; j < 3; j++){
    int c = lane + j*64;
    float s = 0.f;
#pragma unroll
    for (int k = 0; k < 4; k++) s += ys[(((size_t)k*2 + b)*4096 + l)*192 + c];
    v[j] = s;
  }
  float tot = v[0] + v[1] + v[2];
#pragma unroll
  for (int o = 1; o < 64; o <<= 1) tot += __shfl_xor(tot, o);
  float mean = tot * (1.f/192.f);
  float d0 = v[0]-mean, d1 = v[1]-mean, d2 = v[2]-mean;
  float vs = d0*d0 + d1*d1 + d2*d2;
#pragma unroll
  for (int o = 1; o < 64; o <<= 1) vs += __shfl_xor(vs, o);
  float rstd = rsqrtf(vs*(1.f/192.f) + 1e-5f);
  float nd[3] = {d0, d1, d2};
#pragma unroll
  for (int j = 0; j < 3; j++){
    int c = lane + j*64;
    float val = nd[j]*rstd*gamma[c] + beta[c];
    val *= zs[(size_t)row*192 + c];
    yln[(size_t)row*192 + c] = val;
  }
}

// ---------------- Stage 7: out = y_ln @ W_out^T + b_out ----------------
// M=8192, N=96 (pad 128), K=192 (2 chunks). grid(128,2).
__global__ __launch_bounds__(256) void k_gemm_out(
    const float* __restrict__ yln, const float* __restrict__ Wout,
    const float* __restrict__ bout, float* __restrict__ out)
{
  __shared__ float As[64][100];
  __shared__ float Bs[64][100];
  const int m0 = blockIdx.x*64, n0 = blockIdx.y*64;
  const int tid = threadIdx.x;
  const int tx = tid & 15, ty = tid >> 4;
  float acc[4][4] = {};
  for (int kc = 0; kc < 2; kc++){
    __syncthreads();
#pragma unroll
    for (int i = 0; i < 6; i++){
      int idx = tid + i*256;
      int r = idx/24, c4 = idx%24;
      *(float4*)&As[r][c4*4] = *(const float4*)(yln + (size_t)(m0+r)*192 + kc*96 + c4*4);
      int nn = n0 + r;
      float4 wv = make_float4(0.f,0.f,0.f,0.f);
      if (nn < 96) wv = *(const float4*)(Wout + (size_t)nn*192 + kc*96 + c4*4);
      *(float4*)&Bs[r][c4*4] = wv;
    }
    __syncthreads();
    micro_mm<24,100>(As, Bs, tx, ty, acc);
  }
#pragma unroll
  for (int i = 0; i < 4; i++){
    int m = m0 + ty*4 + i;
#pragma unroll
    for (int j = 0; j < 4; j++){
      int n = n0 + tx*4 + j;
      if (n < 96) out[(size_t)m*96 + n] = acc[i][j] + bout[n];
    }
  }
}

extern "C" void kernel_launch(void* const* d_in, const int* in_sizes, int n_in,
                              void* d_out, int out_size, void* d_ws, size_t ws_size,
                              hipStream_t stream)
{
  const float* x      = (const float*)d_in[0];
  const float* W_in   = (const float*)d_in[1];
  const float* b_in   = (const float*)d_in[2];
  const float* conv_w = (const float*)d_in[3];
  const float* conv_b = (const float*)d_in[4];
  const float* W_xp   = (const float*)d_in[5];
  const float* b_xp   = (const float*)d_in[6];
  const float* W_dt   = (const float*)d_in[7];
  const float* b_dt   = (const float*)d_in[8];
  const float* A_log  = (const float*)d_in[9];
  const float* D_skip = (const float*)d_in[10];
  const float* dt_bias= (const float*)d_in[11];
  const float* W_out  = (const float*)d_in[12];
  const float* b_out  = (const float*)d_in[13];
  const float* gamma  = (const float*)d_in[14];
  const float* beta   = (const float*)d_in[15];
  float* out = (float*)d_out;

  float* ws   = (float*)d_ws;
  float* xx   = ws;               // 1572864
  float* zs   = xx  + 1572864;    // 1572864
  float* xc   = zs  + 1572864;    // 1572864
  float* xcT  = xc  + 1572864;    // 1572864
  float* xdbl = xcT + 1572864;    // 1245184
  float* dte  = xdbl+ 1245184;    // 6291456
  float* ysb  = dte + 6291456;    // 6291456
  float* yln  = ysb + 6291456;    // 1572864
  float* Pb   = yln + 1572864;    // 786432
  float* Sb   = Pb  + 786432;     // 786432
  float* H0   = Sb  + 786432;     // 786432  -> total 24051712 floats (~96.2 MB)

  k_gemm_in <<<dim3(128, 6),    256, 0, stream>>>(x, W_in, b_in, xx, zs);
  k_conv    <<<6144,            256, 0, stream>>>(xx, conv_w, conv_b, xc, xcT);
  k_gemm_xdbl<<<dim3(64, 3, 2), 256, 0, stream>>>(xc, xcT, W_xp, b_xp, xdbl);
  k_gemm_dt <<<dim3(64, 12, 2), 256, 0, stream>>>(xdbl, W_dt, b_dt, dt_bias, dte);
  k_scanA   <<<3072,            256, 0, stream>>>(xc, xcT, xdbl, dte, A_log, Pb, Sb);
  k_scanB   <<<96,              256, 0, stream>>>(Pb, Sb, H0);
  k_scanC   <<<3072,            256, 0, stream>>>(xc, xcT, xdbl, dte, A_log, D_skip, H0, ysb);
  k_ln      <<<2048,            256, 0, stream>>>(ysb, zs, gamma, beta, yln);
  k_gemm_out<<<dim3(128, 2),    256, 0, stream>>>(yln, W_out, b_out, out);
}

// Round 2
// 394.336 us; speedup vs baseline: 1.6552x; 1.6552x over previous
//
#include <hip/hip_runtime.h>
#include <cstdint>
#include <cstddef>

// SS2D: B=2, H=W=64 (L=4096), D_MODEL=96, D_INNER=192, K=4 dirs, N=16 states, DT_RANK=6.
// All fp32. Two-pass chunked selective scan (32 chunks x 128 steps).
// R1: GEMM micro-kernel rewritten: limited unroll (no VGPR spills — R0 had VGPR=256 and
// ~470MB of scratch spill traffic on k_gemm_in), B tile stored transposed in LDS
// (conflict-free reads: lane stride 4 dwords = 2-way = free).

__device__ __forceinline__ float siluf(float x){ return x * (1.f/(1.f+__expf(-x))); }

// As[64][STRA]: A tile, row m, k contiguous. BsT[KD][STRB]: B tile transposed, k row, n contiguous.
// acc[i][j] += sum_k A[ty*4+i][k] * B[n=tx*4+j][k]
template<int KD, int STRA, int STRB>
__device__ __forceinline__ void micro_mm_T(const float (&As)[64][STRA], const float (&BsT)[KD][STRB],
                                           int tx, int ty, float (&acc)[4][4])
{
#pragma unroll 2
  for (int k4 = 0; k4 < KD/4; k4++){
    float a[4][4];
#pragma unroll
    for (int i = 0; i < 4; i++){
      float4 t = *(const float4*)&As[ty*4+i][k4*4];
      a[i][0]=t.x; a[i][1]=t.y; a[i][2]=t.z; a[i][3]=t.w;
    }
#pragma unroll
    for (int e = 0; e < 4; e++){
      float4 b = *(const float4*)&BsT[k4*4+e][tx*4];
#pragma unroll
      for (int i = 0; i < 4; i++){
        acc[i][0] = fmaf(a[i][e], b.x, acc[i][0]);
        acc[i][1] = fmaf(a[i][e], b.y, acc[i][1]);
        acc[i][2] = fmaf(a[i][e], b.z, acc[i][2]);
        acc[i][3] = fmaf(a[i][e], b.w, acc[i][3]);
      }
    }
  }
}

// ---------------- Stage 1: xz = x @ W_in^T + b_in; split -> xx, silu(z) ----------------
// M=8192 (B*L), K=96, N=384. grid(128,6), block 256.
__global__ __launch_bounds__(256) void k_gemm_in(
    const float* __restrict__ x, const float* __restrict__ W,
    const float* __restrict__ bias, float* __restrict__ xx, float* __restrict__ zs)
{
  __shared__ float As[64][100];
  __shared__ float BsT[96][68];
  const int m0 = blockIdx.x*64, n0 = blockIdx.y*64;
  const int tid = threadIdx.x;
#pragma unroll
  for (int i = 0; i < 6; i++){
    int idx = tid + i*256;
    { int r = idx/24, c4 = idx%24;
      *(float4*)&As[r][c4*4] = *(const float4*)(x + (size_t)(m0+r)*96 + c4*4); }
    { int r = idx & 63, c4 = idx >> 6;
      float4 wv = *(const float4*)(W + (size_t)(n0+r)*96 + c4*4);
      BsT[c4*4+0][r]=wv.x; BsT[c4*4+1][r]=wv.y; BsT[c4*4+2][r]=wv.z; BsT[c4*4+3][r]=wv.w; }
  }
  __syncthreads();
  const int tx = tid & 15, ty = tid >> 4;
  float acc[4][4] = {};
  micro_mm_T<96,100,68>(As, BsT, tx, ty, acc);
#pragma unroll
  for (int i = 0; i < 4; i++){
    int m = m0 + ty*4 + i;
#pragma unroll
    for (int j = 0; j < 4; j++){
      int n = n0 + tx*4 + j;
      float v = acc[i][j] + bias[n];
      if (n < 192) xx[(size_t)m*192 + n] = v;
      else         zs[(size_t)m*192 + (n-192)] = siluf(v);
    }
  }
}

// ---------------- Stage 2: depthwise 3x3 SAME conv + bias + silu; writes xc and spatial-transposed xcT ----------------
__global__ __launch_bounds__(256) void k_conv(
    const float* __restrict__ xx, const float* __restrict__ cw, const float* __restrict__ cb,
    float* __restrict__ xc, float* __restrict__ xcT)
{
  int gid = blockIdx.x*256 + threadIdx.x;
  int c = gid % 192;
  int l = (gid/192) & 4095;
  int b = gid / (192*4096);
  int h = l >> 6, w = l & 63;
  float s = 0.f;
#pragma unroll
  for (int kh = 0; kh < 3; kh++){
    int h2 = h + kh - 1;
    if ((unsigned)h2 >= 64u) continue;
#pragma unroll
    for (int kw = 0; kw < 3; kw++){
      int w2 = w + kw - 1;
      if ((unsigned)w2 >= 64u) continue;
      s += xx[((size_t)b*4096 + h2*64 + w2)*192 + c] * cw[c*9 + kh*3 + kw];
    }
  }
  s = siluf(s + cb[c]);
  xc[((size_t)b*4096 + l)*192 + c] = s;
  int tl = (l & 63)*64 + (l >> 6);
  xcT[((size_t)b*4096 + tl)*192 + c] = s;
}

// ---------------- Stage 3: x_dbl[b, p(152), l] = W_xp @ concat4(xc views) + b_xp ----------------
// K=768 in 8 chunks of 96 (chunk -> direction kp = kc/2). grid(64, 3, 2), block 256.
// Stored as x_dbl[b][k][l][38] (k = p/38).
__global__ __launch_bounds__(256) void k_gemm_xdbl(
    const float* __restrict__ xc, const float* __restrict__ xcT,
    const float* __restrict__ Wxp, const float* __restrict__ bxp,
    float* __restrict__ xdbl)
{
  __shared__ float As[64][100];
  __shared__ float BsT[96][68];
  const int m0 = blockIdx.x*64;       // l tile
  const int n0 = blockIdx.y*64;       // p tile
  const int b  = blockIdx.z;
  const int tid = threadIdx.x;
  const int tx = tid & 15, ty = tid >> 4;
  float acc[4][4] = {};
  for (int kc = 0; kc < 8; kc++){
    const int kp = kc >> 1, off = (kc & 1)*96;
    const float* src = (kp & 1) ? xcT : xc;
    const bool rev = (kp >= 2);
    __syncthreads();
#pragma unroll
    for (int i = 0; i < 6; i++){
      int idx = tid + i*256;
      { int r = idx/24, c4 = idx%24;
        int l = m0 + r; int ls = rev ? 4095 - l : l;
        *(float4*)&As[r][c4*4] = *(const float4*)(src + ((size_t)b*4096 + ls)*192 + off + c4*4); }
      { int r = idx & 63, c4 = idx >> 6;
        int p = n0 + r;
        float4 wv = make_float4(0.f,0.f,0.f,0.f);
        if (p < 152) wv = *(const float4*)(Wxp + (size_t)p*768 + kp*192 + off + c4*4);
        BsT[c4*4+0][r]=wv.x; BsT[c4*4+1][r]=wv.y; BsT[c4*4+2][r]=wv.z; BsT[c4*4+3][r]=wv.w; }
    }
    __syncthreads();
    micro_mm_T<96,100,68>(As, BsT, tx, ty, acc);
  }
#pragma unroll
  for (int i = 0; i < 4; i++){
    int l = m0 + ty*4 + i;
#pragma unroll
    for (int j = 0; j < 4; j++){
      int p = n0 + tx*4 + j;
      if (p < 152){
        int k = p/38, pp = p%38;
        xdbl[(((size_t)b*4 + k)*4096 + l)*38 + pp] = acc[i][j] + bxp[p];
      }
    }
  }
}

// ---------------- Stage 4: dt_eff = softplus(W_dt @ dts + b_dt + dt_bias) ----------------
// M=4096/b, N=768, K=24. grid(64, 12, 2). Stored dt_eff[b][k][l][192].
__global__ __launch_bounds__(256) void k_gemm_dt(
    const float* __restrict__ xdbl, const float* __restrict__ Wdt,
    const float* __restrict__ bdt, const float* __restrict__ dtbias,
    float* __restrict__ dte)
{
  __shared__ float As[64][28];
  __shared__ float BsT[24][68];
  const int m0 = blockIdx.x*64;
  const int n0 = blockIdx.y*64;
  const int b  = blockIdx.z;
  const int tid = threadIdx.x;
#pragma unroll
  for (int i = 0; i < 6; i++){
    int idx = tid + i*256;
    { int r = idx/24, cc = idx%24;
      int kp = cc/6, ri = cc%6;
      As[r][cc] = xdbl[(((size_t)b*4 + kp)*4096 + (m0+r))*38 + ri]; }
    { int r = idx & 63, cc = idx >> 6;
      BsT[cc][r] = Wdt[(size_t)(n0+r)*24 + cc]; }
  }
  __syncthreads();
  const int tx = tid & 15, ty = tid >> 4;
  float acc[4][4] = {};
  micro_mm_T<24,28,68>(As, BsT, tx, ty, acc);
#pragma unroll
  for (int i = 0; i < 4; i++){
    int l = m0 + ty*4 + i;
#pragma unroll
    for (int j = 0; j < 4; j++){
      int c = n0 + tx*4 + j;
      float v = acc[i][j] + bdt[c] + dtbias[c];
      v = (v > 20.f) ? v : log1pf(__expf(v));
      dte[(((size_t)b*4 + c/192)*4096 + l)*192 + (c%192)] = v;
    }
  }
}

// ---------------- Selective scan, two-pass chunked ----------------
// wave = 64 lanes: lane = didx*16 + n; 4 channels/wave, 16 states/channel.
// wid = ((b*4+k)*48 + dg)*32 + chunk; 12288 wids, 4 waves/block -> 3072 blocks.
__global__ __launch_bounds__(256) void k_scanA(
    const float* __restrict__ xc, const float* __restrict__ xcT,
    const float* __restrict__ xdbl, const float* __restrict__ dte,
    const float* __restrict__ A_log,
    float* __restrict__ Pb, float* __restrict__ Sb)
{
  const int lane = threadIdx.x & 63;
  const int wid  = blockIdx.x*4 + (threadIdx.x >> 6);
  int tmp = wid;
  const int ck = tmp & 31; tmp >>= 5;
  const int dg = tmp % 48; tmp /= 48;
  const int k  = tmp & 3;
  const int b  = tmp >> 2;
  const int n = lane & 15, didx = lane >> 4;
  const int d = dg*4 + didx, ch = k*192 + d;
  const float An = -__expf(A_log[ch*16 + n]);
  const int l0 = ck*128;
  const float* srcb = (k & 1) ? xcT : xc;
  const bool rev = (k >= 2);
  const float* dtp = dte  + (((size_t)b*4 + k)*4096 + l0)*192 + d;
  const float* xdp = xdbl + (((size_t)b*4 + k)*4096 + l0)*38;
  const float* up  = srcb + ((size_t)b*4096 + (rev ? 4095 - l0 : l0))*192 + d;
  const int ustride = rev ? -192 : 192;
  float h = 0.f, P = 1.f;
  for (int t = 0; t < 128; t++){
    float dt = dtp[0];
    float u  = up[0];
    float Bv = xdp[6 + n];
    float dA = __expf(dt*An);
    h = dA*h + (dt*u)*Bv;
    P *= dA;
    dtp += 192; xdp += 38; up += ustride;
  }
  Pb[(size_t)wid*64 + lane] = P;
  Sb[(size_t)wid*64 + lane] = h;
}

__global__ __launch_bounds__(256) void k_scanB(
    const float* __restrict__ Pb, const float* __restrict__ Sb, float* __restrict__ H0)
{
  int sid = blockIdx.x*256 + threadIdx.x;   // 24576 states
  int lane = sid & 63; int rest = sid >> 6;
  int dg = rest % 48; rest /= 48;
  int k = rest & 3; int b = rest >> 2;
  size_t base = ((((size_t)b*4 + k)*48 + dg)*32)*64 + lane;
  float h = 0.f;
  for (int ck = 0; ck < 32; ck++){
    size_t idx = base + (size_t)ck*64;
    H0[idx] = h;
    h = Pb[idx]*h + Sb[idx];
  }
}

__global__ __launch_bounds__(256) void k_scanC(
    const float* __restrict__ xc, const float* __restrict__ xcT,
    const float* __restrict__ xdbl, const float* __restrict__ dte,
    const float* __restrict__ A_log, const float* __restrict__ Dskip,
    const float* __restrict__ H0, float* __restrict__ ys)
{
  const int lane = threadIdx.x & 63;
  const int wid  = blockIdx.x*4 + (threadIdx.x >> 6);
  int tmp = wid;
  const int ck = tmp & 31; tmp >>= 5;
  const int dg = tmp % 48; tmp /= 48;
  const int k  = tmp & 3;
  const int b  = tmp >> 2;
  const int n = lane & 15, didx = lane >> 4;
  const int d = dg*4 + didx, ch = k*192 + d;
  const float An = -__expf(A_log[ch*16 + n]);
  const float Dv = Dskip[ch];
  const int l0 = ck*128;
  const float* srcb = (k & 1) ? xcT : xc;
  const bool rev = (k >= 2);
  const float* dtp = dte  + (((size_t)b*4 + k)*4096 + l0)*192 + d;
  const float* xdp = xdbl + (((size_t)b*4 + k)*4096 + l0)*38;
  const float* up  = srcb + ((size_t)b*4096 + (rev ? 4095 - l0 : l0))*192 + d;
  const int ustride = rev ? -192 : 192;
  float h = H0[(size_t)wid*64 + lane];
  for (int t = 0; t < 128; t++){
    int l = l0 + t;
    float dt = dtp[0];
    float u  = up[0];
    float Bv = xdp[6 + n];
    float Cv = xdp[22 + n];
    float dA = __expf(dt*An);
    h = dA*h + (dt*u)*Bv;
    float p = h*Cv;
    p += __shfl_xor(p, 1);
    p += __shfl_xor(p, 2);
    p += __shfl_xor(p, 4);
    p += __shfl_xor(p, 8);
    if (n == 0){
      float y = p + u*Dv;
      int pos;
      if (k == 0)      pos = l;
      else if (k == 1) pos = (l & 63)*64 + (l >> 6);
      else { int l2 = 4095 - l; pos = (k == 2) ? l2 : ((l2 & 63)*64 + (l2 >> 6)); }
      ys[(((size_t)k*2 + b)*4096 + pos)*192 + d] = y;
    }
    dtp += 192; xdp += 38; up += ustride;
  }
}

// ---------------- Stage 6: merge 4 planes + LayerNorm(gamma,beta) * silu(z) ----------------
// One wave per row; 4 rows/block. grid 2048.
__global__ __launch_bounds__(256) void k_ln(
    const float* __restrict__ ys, const float* __restrict__ zs,
    const float* __restrict__ gamma, const float* __restrict__ beta,
    float* __restrict__ yln)
{
  int row = blockIdx.x*4 + (threadIdx.x >> 6);
  int lane = threadIdx.x & 63;
  int b = row >> 12; int l = row & 4095;
  float v[3];
#pragma unroll
  for (int j = 0; j < 3; j++){
    int c = lane + j*64;
    float s = 0.f;
#pragma unroll
    for (int k = 0; k < 4; k++) s += ys[(((size_t)k*2 + b)*4096 + l)*192 + c];
    v[j] = s;
  }
  float tot = v[0] + v[1] + v[2];
#pragma unroll
  for (int o = 1; o < 64; o <<= 1) tot += __shfl_xor(tot, o);
  float mean = tot * (1.f/192.f);
  float d0 = v[0]-mean, d1 = v[1]-mean, d2 = v[2]-mean;
  float vs = d0*d0 + d1*d1 + d2*d2;
#pragma unroll
  for (int o = 1; o < 64; o <<= 1) vs += __shfl_xor(vs, o);
  float rstd = rsqrtf(vs*(1.f/192.f) + 1e-5f);
  float nd[3] = {d0, d1, d2};
#pragma unroll
  for (int j = 0; j < 3; j++){
    int c = lane + j*64;
    float val = nd[j]*rstd*gamma[c] + beta[c];
    val *= zs[(size_t)row*192 + c];
    yln[(size_t)row*192 + c] = val;
  }
}

// ---------------- Stage 7: out = y_ln @ W_out^T + b_out ----------------
// M=8192, N=96 (pad 64-tile x2), K=192 (2 chunks). grid(128,2).
__global__ __launch_bounds__(256) void k_gemm_out(
    const float* __restrict__ yln, const float* __restrict__ Wout,
    const float* __restrict__ bout, float* __restrict__ out)
{
  __shared__ float As[64][100];
  __shared__ float BsT[96][68];
  const int m0 = blockIdx.x*64, n0 = blockIdx.y*64;
  const int tid = threadIdx.x;
  const int tx = tid & 15, ty = tid >> 4;
  float acc[4][4] = {};
  for (int kc = 0; kc < 2; kc++){
    __syncthreads();
#pragma unroll
    for (int i = 0; i < 6; i++){
      int idx = tid + i*256;
      { int r = idx/24, c4 = idx%24;
        *(float4*)&As[r][c4*4] = *(const float4*)(yln + (size_t)(m0+r)*192 + kc*96 + c4*4); }
      { int r = idx & 63, c4 = idx >> 6;
        int nn = n0 + r;
        float4 wv = make_float4(0.f,0.f,0.f,0.f);
        if (nn < 96) wv = *(const float4*)(Wout + (size_t)nn*192 + kc*96 + c4*4);
        BsT[c4*4+0][r]=wv.x; BsT[c4*4+1][r]=wv.y; BsT[c4*4+2][r]=wv.z; BsT[c4*4+3][r]=wv.w; }
    }
    __syncthreads();
    micro_mm_T<96,100,68>(As, BsT, tx, ty, acc);
  }
#pragma unroll
  for (int i = 0; i < 4; i++){
    int m = m0 + ty*4 + i;
#pragma unroll
    for (int j = 0; j < 4; j++){
      int n = n0 + tx*4 + j;
      if (n < 96) out[(size_t)m*96 + n] = acc[i][j] + bout[n];
    }
  }
}

extern "C" void kernel_launch(void* const* d_in, const int* in_sizes, int n_in,
                              void* d_out, int out_size, void* d_ws, size_t ws_size,
                              hipStream_t stream)
{
  const float* x      = (const float*)d_in[0];
  const float* W_in   = (const float*)d_in[1];
  const float* b_in   = (const float*)d_in[2];
  const float* conv_w = (const float*)d_in[3];
  const float* conv_b = (const float*)d_in[4];
  const float* W_xp   = (const float*)d_in[5];
  const float* b_xp   = (const float*)d_in[6];
  const float* W_dt   = (const float*)d_in[7];
  const float* b_dt   = (const float*)d_in[8];
  const float* A_log  = (const float*)d_in[9];
  const float* D_skip = (const float*)d_in[10];
  const float* dt_bias= (const float*)d_in[11];
  const float* W_out  = (const float*)d_in[12];
  const float* b_out  = (const float*)d_in[13];
  const float* gamma  = (const float*)d_in[14];
  const float* beta   = (const float*)d_in[15];
  float* out = (float*)d_out;

  float* ws   = (float*)d_ws;
  float* xx   = ws;               // 1572864
  float* zs   = xx  + 1572864;    // 1572864
  float* xc   = zs  + 1572864;    // 1572864
  float* xcT  = xc  + 1572864;    // 1572864
  float* xdbl = xcT + 1572864;    // 1245184
  float* dte  = xdbl+ 1245184;    // 6291456
  float* ysb  = dte + 6291456;    // 6291456
  float* yln  = ysb + 6291456;    // 1572864
  float* Pb   = yln + 1572864;    // 786432
  float* Sb   = Pb  + 786432;     // 786432
  float* H0   = Sb  + 786432;     // 786432  -> total 24051712 floats (~96.2 MB)

  k_gemm_in <<<dim3(128, 6),    256, 0, stream>>>(x, W_in, b_in, xx, zs);
  k_conv    <<<6144,            256, 0, stream>>>(xx, conv_w, conv_b, xc, xcT);
  k_gemm_xdbl<<<dim3(64, 3, 2), 256, 0, stream>>>(xc, xcT, W_xp, b_xp, xdbl);
  k_gemm_dt <<<dim3(64, 12, 2), 256, 0, stream>>>(xdbl, W_dt, b_dt, dt_bias, dte);
  k_scanA   <<<3072,            256, 0, stream>>>(xc, xcT, xdbl, dte, A_log, Pb, Sb);
  k_scanB   <<<96,              256, 0, stream>>>(Pb, Sb, H0);
  k_scanC   <<<3072,            256, 0, stream>>>(xc, xcT, xdbl, dte, A_log, D_skip, H0, ysb);
  k_ln      <<<2048,            256, 0, stream>>>(ysb, zs, gamma, beta, yln);
  k_gemm_out<<<dim3(128, 2),    256, 0, stream>>>(yln, W_out, b_out, out);
}

// Round 3
// 315.427 us; speedup vs baseline: 2.0693x; 1.2502x over previous
//
#include <hip/hip_runtime.h>
#include <cstdint>
#include <cstddef>

// SS2D: B=2, H=W=64 (L=4096), D_MODEL=96, D_INNER=192, K=4 dirs, N=16 states, DT_RANK=6.
// All fp32.
// R1: GEMMs: limited unroll (no spills), transposed B tile in LDS (no bank conflicts).
// R2: scan rewritten: lane = channel d, 16 states in-register per lane -> no shuffles,
//     full 16-way ILP, coalesced 256B loads/stores. x_dbl repacked to stride 48
//     (dts@0, B@8, C@24) for aligned float4 uniform loads. Chunked scan: 64 chunks x 64.
// ws: 94.4 MB (Pb aliases xx, Sb aliases yln).

#define CHUNK 64
#define NCK   64   // 4096 / CHUNK

__device__ __forceinline__ float siluf(float x){ return x * (1.f/(1.f+__expf(-x))); }

template<int KD, int STRA, int STRB>
__device__ __forceinline__ void micro_mm_T(const float (&As)[64][STRA], const float (&BsT)[KD][STRB],
                                           int tx, int ty, float (&acc)[4][4])
{
#pragma unroll 2
  for (int k4 = 0; k4 < KD/4; k4++){
    float a[4][4];
#pragma unroll
    for (int i = 0; i < 4; i++){
      float4 t = *(const float4*)&As[ty*4+i][k4*4];
      a[i][0]=t.x; a[i][1]=t.y; a[i][2]=t.z; a[i][3]=t.w;
    }
#pragma unroll
    for (int e = 0; e < 4; e++){
      float4 b = *(const float4*)&BsT[k4*4+e][tx*4];
#pragma unroll
      for (int i = 0; i < 4; i++){
        acc[i][0] = fmaf(a[i][e], b.x, acc[i][0]);
        acc[i][1] = fmaf(a[i][e], b.y, acc[i][1]);
        acc[i][2] = fmaf(a[i][e], b.z, acc[i][2]);
        acc[i][3] = fmaf(a[i][e], b.w, acc[i][3]);
      }
    }
  }
}

// ---------------- Stage 1: xz = x @ W_in^T + b_in; split -> xx, silu(z) ----------------
__global__ __launch_bounds__(256) void k_gemm_in(
    const float* __restrict__ x, const float* __restrict__ W,
    const float* __restrict__ bias, float* __restrict__ xx, float* __restrict__ zs)
{
  __shared__ float As[64][100];
  __shared__ float BsT[96][68];
  const int m0 = blockIdx.x*64, n0 = blockIdx.y*64;
  const int tid = threadIdx.x;
#pragma unroll
  for (int i = 0; i < 6; i++){
    int idx = tid + i*256;
    { int r = idx/24, c4 = idx%24;
      *(float4*)&As[r][c4*4] = *(const float4*)(x + (size_t)(m0+r)*96 + c4*4); }
    { int r = idx & 63, c4 = idx >> 6;
      float4 wv = *(const float4*)(W + (size_t)(n0+r)*96 + c4*4);
      BsT[c4*4+0][r]=wv.x; BsT[c4*4+1][r]=wv.y; BsT[c4*4+2][r]=wv.z; BsT[c4*4+3][r]=wv.w; }
  }
  __syncthreads();
  const int tx = tid & 15, ty = tid >> 4;
  float acc[4][4] = {};
  micro_mm_T<96,100,68>(As, BsT, tx, ty, acc);
#pragma unroll
  for (int i = 0; i < 4; i++){
    int m = m0 + ty*4 + i;
#pragma unroll
    for (int j = 0; j < 4; j++){
      int n = n0 + tx*4 + j;
      float v = acc[i][j] + bias[n];
      if (n < 192) xx[(size_t)m*192 + n] = v;
      else         zs[(size_t)m*192 + (n-192)] = siluf(v);
    }
  }
}

// ---------------- Stage 2: depthwise 3x3 conv + silu; writes xc and transposed xcT ----------------
__global__ __launch_bounds__(256) void k_conv(
    const float* __restrict__ xx, const float* __restrict__ cw, const float* __restrict__ cb,
    float* __restrict__ xc, float* __restrict__ xcT)
{
  int gid = blockIdx.x*256 + threadIdx.x;
  int c = gid % 192;
  int l = (gid/192) & 4095;
  int b = gid / (192*4096);
  int h = l >> 6, w = l & 63;
  float s = 0.f;
#pragma unroll
  for (int kh = 0; kh < 3; kh++){
    int h2 = h + kh - 1;
    if ((unsigned)h2 >= 64u) continue;
#pragma unroll
    for (int kw = 0; kw < 3; kw++){
      int w2 = w + kw - 1;
      if ((unsigned)w2 >= 64u) continue;
      s += xx[((size_t)b*4096 + h2*64 + w2)*192 + c] * cw[c*9 + kh*3 + kw];
    }
  }
  s = siluf(s + cb[c]);
  xc[((size_t)b*4096 + l)*192 + c] = s;
  int tl = (l & 63)*64 + (l >> 6);
  xcT[((size_t)b*4096 + tl)*192 + c] = s;
}

// ---------------- Stage 3: x_dbl = W_xp @ concat4(xc views) + b_xp ----------------
// Stored as x_dbl[b][k][l][48]: dts@0..5, B@8..23, C@24..39 (16B-aligned float4 slots).
__global__ __launch_bounds__(256) void k_gemm_xdbl(
    const float* __restrict__ xc, const float* __restrict__ xcT,
    const float* __restrict__ Wxp, const float* __restrict__ bxp,
    float* __restrict__ xdbl)
{
  __shared__ float As[64][100];
  __shared__ float BsT[96][68];
  const int m0 = blockIdx.x*64;       // l tile
  const int n0 = blockIdx.y*64;       // p tile
  const int b  = blockIdx.z;
  const int tid = threadIdx.x;
  const int tx = tid & 15, ty = tid >> 4;
  float acc[4][4] = {};
  for (int kc = 0; kc < 8; kc++){
    const int kp = kc >> 1, off = (kc & 1)*96;
    const float* src = (kp & 1) ? xcT : xc;
    const bool rev = (kp >= 2);
    __syncthreads();
#pragma unroll
    for (int i = 0; i < 6; i++){
      int idx = tid + i*256;
      { int r = idx/24, c4 = idx%24;
        int l = m0 + r; int ls = rev ? 4095 - l : l;
        *(float4*)&As[r][c4*4] = *(const float4*)(src + ((size_t)b*4096 + ls)*192 + off + c4*4); }
      { int r = idx & 63, c4 = idx >> 6;
        int p = n0 + r;
        float4 wv = make_float4(0.f,0.f,0.f,0.f);
        if (p < 152) wv = *(const float4*)(Wxp + (size_t)p*768 + kp*192 + off + c4*4);
        BsT[c4*4+0][r]=wv.x; BsT[c4*4+1][r]=wv.y; BsT[c4*4+2][r]=wv.z; BsT[c4*4+3][r]=wv.w; }
    }
    __syncthreads();
    micro_mm_T<96,100,68>(As, BsT, tx, ty, acc);
  }
#pragma unroll
  for (int i = 0; i < 4; i++){
    int l = m0 + ty*4 + i;
#pragma unroll
    for (int j = 0; j < 4; j++){
      int p = n0 + tx*4 + j;
      if (p < 152){
        int k = p/38, pp = p%38;
        int off = (pp < 6) ? pp : pp + 2;
        xdbl[(((size_t)b*4 + k)*4096 + l)*48 + off] = acc[i][j] + bxp[p];
      }
    }
  }
}

// ---------------- Stage 4: dt_eff = softplus(W_dt @ dts + b_dt + dt_bias) ----------------
__global__ __launch_bounds__(256) void k_gemm_dt(
    const float* __restrict__ xdbl, const float* __restrict__ Wdt,
    const float* __restrict__ bdt, const float* __restrict__ dtbias,
    float* __restrict__ dte)
{
  __shared__ float As[64][28];
  __shared__ float BsT[24][68];
  const int m0 = blockIdx.x*64;
  const int n0 = blockIdx.y*64;
  const int b  = blockIdx.z;
  const int tid = threadIdx.x;
#pragma unroll
  for (int i = 0; i < 6; i++){
    int idx = tid + i*256;
    { int r = idx/24, cc = idx%24;
      int kp = cc/6, ri = cc%6;
      As[r][cc] = xdbl[(((size_t)b*4 + kp)*4096 + (m0+r))*48 + ri]; }
    { int r = idx & 63, cc = idx >> 6;
      BsT[cc][r] = Wdt[(size_t)(n0+r)*24 + cc]; }
  }
  __syncthreads();
  const int tx = tid & 15, ty = tid >> 4;
  float acc[4][4] = {};
  micro_mm_T<24,28,68>(As, BsT, tx, ty, acc);
#pragma unroll
  for (int i = 0; i < 4; i++){
    int l = m0 + ty*4 + i;
#pragma unroll
    for (int j = 0; j < 4; j++){
      int c = n0 + tx*4 + j;
      float v = acc[i][j] + bdt[c] + dtbias[c];
      v = (v > 20.f) ? v : log1pf(__expf(v));
      dte[(((size_t)b*4 + c/192)*4096 + l)*192 + (c%192)] = v;
    }
  }
}

// ---------------- Selective scan: lane = channel d, 16 states in-register ----------------
// wave: 64 lanes = 64 contiguous channels. group g = (b,k,dblk): 24 groups.
// wid = g*NCK + ck; 1536 waves, 4/block -> 384 blocks.
// Pb/Sb/H0 layout: [(wid*16 + n)*64 + lane].
__global__ __launch_bounds__(256) void k_scanA(
    const float* __restrict__ xc, const float* __restrict__ xcT,
    const float* __restrict__ xdbl, const float* __restrict__ dte,
    const float* __restrict__ A_log,
    float* __restrict__ Pb, float* __restrict__ Sb)
{
  const int lane = threadIdx.x & 63;
  const int wid  = blockIdx.x*4 + (threadIdx.x >> 6);
  const int ck = wid & (NCK-1); const int g = wid / NCK;
  const int dblk = g % 3; const int bk = g / 3;
  const int k = bk & 3; const int b = bk >> 2;
  const int d = dblk*64 + lane; const int ch = k*192 + d;
  float An[16];
  {
    const float4* ap = (const float4*)(A_log + (size_t)ch*16);
#pragma unroll
    for (int i = 0; i < 4; i++){
      float4 t = ap[i];
      An[4*i+0] = -__expf(t.x); An[4*i+1] = -__expf(t.y);
      An[4*i+2] = -__expf(t.z); An[4*i+3] = -__expf(t.w);
    }
  }
  const int l0 = ck*CHUNK;
  const bool rev = (k >= 2);
  const float* srcb = (k & 1) ? xcT : xc;
  const float* dtp = dte  + (((size_t)b*4 + k)*4096 + l0)*192 + d;
  const float* xdp = xdbl + (((size_t)b*4 + k)*4096 + l0)*48;
  const float* up  = srcb + ((size_t)b*4096 + (rev ? 4095 - l0 : l0))*192 + d;
  const int ust = rev ? -192 : 192;
  float h[16];
#pragma unroll
  for (int n = 0; n < 16; n++) h[n] = 0.f;
  float sdt = 0.f;
#pragma unroll 2
  for (int t = 0; t < CHUNK; t++){
    float dt = dtp[0];
    float u  = up[0];
    float4 B0 = *(const float4*)(xdp + 8);
    float4 B1 = *(const float4*)(xdp + 12);
    float4 B2 = *(const float4*)(xdp + 16);
    float4 B3 = *(const float4*)(xdp + 20);
    float Bv[16] = {B0.x,B0.y,B0.z,B0.w, B1.x,B1.y,B1.z,B1.w,
                    B2.x,B2.y,B2.z,B2.w, B3.x,B3.y,B3.z,B3.w};
    float dtu = dt*u;
    sdt += dt;
#pragma unroll
    for (int n = 0; n < 16; n++){
      float dA = __expf(dt*An[n]);
      h[n] = fmaf(dA, h[n], dtu*Bv[n]);
    }
    dtp += 192; xdp += 48; up += ust;
  }
  size_t base = ((size_t)wid*16)*64 + lane;
#pragma unroll
  for (int n = 0; n < 16; n++){
    Pb[base + n*64] = __expf(An[n]*sdt);
    Sb[base + n*64] = h[n];
  }
}

__global__ __launch_bounds__(256) void k_scanB(
    const float* __restrict__ Pb, const float* __restrict__ Sb, float* __restrict__ H0)
{
  int tid = blockIdx.x*256 + threadIdx.x;  // 24576 = 24 groups * 16 n * 64 lanes
  int lane = tid & 63; int n = (tid >> 6) & 15; int g = tid >> 10;
  float h = 0.f;
  for (int ck = 0; ck < NCK; ck++){
    size_t idx = (((size_t)(g*NCK + ck)*16) + n)*64 + lane;
    H0[idx] = h;
    h = fmaf(Pb[idx], h, Sb[idx]);
  }
}

__global__ __launch_bounds__(256) void k_scanC(
    const float* __restrict__ xc, const float* __restrict__ xcT,
    const float* __restrict__ xdbl, const float* __restrict__ dte,
    const float* __restrict__ A_log, const float* __restrict__ Dskip,
    const float* __restrict__ H0, float* __restrict__ ys)
{
  const int lane = threadIdx.x & 63;
  const int wid  = blockIdx.x*4 + (threadIdx.x >> 6);
  const int ck = wid & (NCK-1); const int g = wid / NCK;
  const int dblk = g % 3; const int bk = g / 3;
  const int k = bk & 3; const int b = bk >> 2;
  const int d = dblk*64 + lane; const int ch = k*192 + d;
  float An[16];
  {
    const float4* ap = (const float4*)(A_log + (size_t)ch*16);
#pragma unroll
    for (int i = 0; i < 4; i++){
      float4 t = ap[i];
      An[4*i+0] = -__expf(t.x); An[4*i+1] = -__expf(t.y);
      An[4*i+2] = -__expf(t.z); An[4*i+3] = -__expf(t.w);
    }
  }
  const float Dv = Dskip[ch];
  const int l0 = ck*CHUNK;
  const bool rev = (k >= 2);
  const float* srcb = (k & 1) ? xcT : xc;
  const float* dtp = dte  + (((size_t)b*4 + k)*4096 + l0)*192 + d;
  const float* xdp = xdbl + (((size_t)b*4 + k)*4096 + l0)*48;
  const float* up  = srcb + ((size_t)b*4096 + (rev ? 4095 - l0 : l0))*192 + d;
  const int ust = rev ? -192 : 192;
  float* ysb = ys + ((size_t)(k*2 + b))*4096*192 + d;
  float h[16];
  size_t base = ((size_t)wid*16)*64 + lane;
#pragma unroll
  for (int n = 0; n < 16; n++) h[n] = H0[base + n*64];
#pragma unroll 2
  for (int t = 0; t < CHUNK; t++){
    int l = l0 + t;
    float dt = dtp[0];
    float u  = up[0];
    float4 B0 = *(const float4*)(xdp + 8);
    float4 B1 = *(const float4*)(xdp + 12);
    float4 B2 = *(const float4*)(xdp + 16);
    float4 B3 = *(const float4*)(xdp + 20);
    float4 C0 = *(const float4*)(xdp + 24);
    float4 C1 = *(const float4*)(xdp + 28);
    float4 C2 = *(const float4*)(xdp + 32);
    float4 C3 = *(const float4*)(xdp + 36);
    float Bv[16] = {B0.x,B0.y,B0.z,B0.w, B1.x,B1.y,B1.z,B1.w,
                    B2.x,B2.y,B2.z,B2.w, B3.x,B3.y,B3.z,B3.w};
    float Cv[16] = {C0.x,C0.y,C0.z,C0.w, C1.x,C1.y,C1.z,C1.w,
                    C2.x,C2.y,C2.z,C2.w, C3.x,C3.y,C3.z,C3.w};
    float dtu = dt*u;
    float y = u*Dv;
#pragma unroll
    for (int n = 0; n < 16; n++){
      float dA = __expf(dt*An[n]);
      h[n] = fmaf(dA, h[n], dtu*Bv[n]);
      y = fmaf(h[n], Cv[n], y);
    }
    int pos;
    if (k == 0)      pos = l;
    else if (k == 1) pos = (l & 63)*64 + (l >> 6);
    else { int l2 = 4095 - l; pos = (k == 2) ? l2 : ((l2 & 63)*64 + (l2 >> 6)); }
    ysb[(size_t)pos*192] = y;
    dtp += 192; xdp += 48; up += ust;
  }
}

// ---------------- Stage 6: merge 4 planes + LayerNorm * silu(z) ----------------
__global__ __launch_bounds__(256) void k_ln(
    const float* __restrict__ ys, const float* __restrict__ zs,
    const float* __restrict__ gamma, const float* __restrict__ beta,
    float* __restrict__ yln)
{
  int row = blockIdx.x*4 + (threadIdx.x >> 6);
  int lane = threadIdx.x & 63;
  int b = row >> 12; int l = row & 4095;
  float v[3];
#pragma unroll
  for (int j = 0; j < 3; j++){
    int c = lane + j*64;
    float s = 0.f;
#pragma unroll
    for (int k = 0; k < 4; k++) s += ys[(((size_t)k*2 + b)*4096 + l)*192 + c];
    v[j] = s;
  }
  float tot = v[0] + v[1] + v[2];
#pragma unroll
  for (int o = 1; o < 64; o <<= 1) tot += __shfl_xor(tot, o);
  float mean = tot * (1.f/192.f);
  float d0 = v[0]-mean, d1 = v[1]-mean, d2 = v[2]-mean;
  float vs = d0*d0 + d1*d1 + d2*d2;
#pragma unroll
  for (int o = 1; o < 64; o <<= 1) vs += __shfl_xor(vs, o);
  float rstd = rsqrtf(vs*(1.f/192.f) + 1e-5f);
  float nd[3] = {d0, d1, d2};
#pragma unroll
  for (int j = 0; j < 3; j++){
    int c = lane + j*64;
    float val = nd[j]*rstd*gamma[c] + beta[c];
    val *= zs[(size_t)row*192 + c];
    yln[(size_t)row*192 + c] = val;
  }
}

// ---------------- Stage 7: out = y_ln @ W_out^T + b_out ----------------
__global__ __launch_bounds__(256) void k_gemm_out(
    const float* __restrict__ yln, const float* __restrict__ Wout,
    const float* __restrict__ bout, float* __restrict__ out)
{
  __shared__ float As[64][100];
  __shared__ float BsT[96][68];
  const int m0 = blockIdx.x*64, n0 = blockIdx.y*64;
  const int tid = threadIdx.x;
  const int tx = tid & 15, ty = tid >> 4;
  float acc[4][4] = {};
  for (int kc = 0; kc < 2; kc++){
    __syncthreads();
#pragma unroll
    for (int i = 0; i < 6; i++){
      int idx = tid + i*256;
      { int r = idx/24, c4 = idx%24;
        *(float4*)&As[r][c4*4] = *(const float4*)(yln + (size_t)(m0+r)*192 + kc*96 + c4*4); }
      { int r = idx & 63, c4 = idx >> 6;
        int nn = n0 + r;
        float4 wv = make_float4(0.f,0.f,0.f,0.f);
        if (nn < 96) wv = *(const float4*)(Wout + (size_t)nn*192 + kc*96 + c4*4);
        BsT[c4*4+0][r]=wv.x; BsT[c4*4+1][r]=wv.y; BsT[c4*4+2][r]=wv.z; BsT[c4*4+3][r]=wv.w; }
    }
    __syncthreads();
    micro_mm_T<96,100,68>(As, BsT, tx, ty, acc);
  }
#pragma unroll
  for (int i = 0; i < 4; i++){
    int m = m0 + ty*4 + i;
#pragma unroll
    for (int j = 0; j < 4; j++){
      int n = n0 + tx*4 + j;
      if (n < 96) out[(size_t)m*96 + n] = acc[i][j] + bout[n];
    }
  }
}

extern "C" void kernel_launch(void* const* d_in, const int* in_sizes, int n_in,
                              void* d_out, int out_size, void* d_ws, size_t ws_size,
                              hipStream_t stream)
{
  const float* x      = (const float*)d_in[0];
  const float* W_in   = (const float*)d_in[1];
  const float* b_in   = (const float*)d_in[2];
  const float* conv_w = (const float*)d_in[3];
  const float* conv_b = (const float*)d_in[4];
  const float* W_xp   = (const float*)d_in[5];
  const float* b_xp   = (const float*)d_in[6];
  const float* W_dt   = (const float*)d_in[7];
  const float* b_dt   = (const float*)d_in[8];
  const float* A_log  = (const float*)d_in[9];
  const float* D_skip = (const float*)d_in[10];
  const float* dt_bias= (const float*)d_in[11];
  const float* W_out  = (const float*)d_in[12];
  const float* b_out  = (const float*)d_in[13];
  const float* gamma  = (const float*)d_in[14];
  const float* beta   = (const float*)d_in[15];
  float* out = (float*)d_out;

  float* ws   = (float*)d_ws;
  float* xx   = ws;               // 1572864 (dead after conv -> Pb)
  float* zs   = xx  + 1572864;    // 1572864
  float* xc   = zs  + 1572864;    // 1572864
  float* xcT  = xc  + 1572864;    // 1572864
  float* xdbl = xcT + 1572864;    // 2*4*4096*48 = 1572864
  float* dte  = xdbl+ 1572864;    // 6291456
  float* ysb  = dte + 6291456;    // 6291456
  float* yln  = ysb + 6291456;    // 1572864 (written only at ln -> Sb before that)
  float* H0   = yln + 1572864;    // 1536*16*64 = 1572864  -> total 23592960 fl (94.4MB)
  float* Pb   = xx;               // alias: 1536*16*64 = 1572864 ✓
  float* Sb   = yln;              // alias ✓

  k_gemm_in  <<<dim3(128, 6),    256, 0, stream>>>(x, W_in, b_in, xx, zs);
  k_conv     <<<6144,            256, 0, stream>>>(xx, conv_w, conv_b, xc, xcT);
  k_gemm_xdbl<<<dim3(64, 3, 2),  256, 0, stream>>>(xc, xcT, W_xp, b_xp, xdbl);
  k_gemm_dt  <<<dim3(64, 12, 2), 256, 0, stream>>>(xdbl, W_dt, b_dt, dt_bias, dte);
  k_scanA    <<<384,             256, 0, stream>>>(xc, xcT, xdbl, dte, A_log, Pb, Sb);
  k_scanB    <<<96,              256, 0, stream>>>(Pb, Sb, H0);
  k_scanC    <<<384,             256, 0, stream>>>(xc, xcT, xdbl, dte, A_log, D_skip, H0, ysb);
  k_ln       <<<2048,            256, 0, stream>>>(ysb, zs, gamma, beta, yln);
  k_gemm_out <<<dim3(128, 2),    256, 0, stream>>>(yln, W_out, b_out, out);
}

// Round 4
// 281.119 us; speedup vs baseline: 2.3218x; 1.1220x over previous
//
#include <hip/hip_runtime.h>
#include <cstdint>
#include <cstddef>

// SS2D: B=2, H=W=64 (L=4096), D_MODEL=96, D_INNER=192, K=4 dirs, N=16 states, DT_RANK=6.
// R1: GEMMs: limited unroll (no spills), transposed B tile in LDS (no bank conflicts).
// R2: scan: lane = channel, 16 states in-register, no shuffles; x_dbl packed stride 48.
// R3: k_gemm_xdbl -> bf16 MFMA 16x16x32 (was LDS-issue-bound fp32 at 59us).
//     A-frags direct from global (contiguous 8-ch bf16), W_xp pre-packed fragment-order.
// ws: 94.4 MB (Pb aliases xx, Sb aliases yln, xcb/xcTb alias ysb, Wf aliases H0).

#define CHUNK 64
#define NCK   64   // 4096 / CHUNK

typedef __attribute__((ext_vector_type(8))) short short8;
typedef __attribute__((ext_vector_type(8))) unsigned short ushort8;
typedef __attribute__((ext_vector_type(4))) float f32x4;

__device__ __forceinline__ float siluf(float x){ return x * (1.f/(1.f+__expf(-x))); }
__device__ __forceinline__ unsigned short f2b(float f){
  uint32_t u = __float_as_uint(f);
  uint32_t r = (u + 0x7fffu + ((u>>16)&1u)) >> 16;
  return (unsigned short)r;
}

template<int KD, int STRA, int STRB>
__device__ __forceinline__ void micro_mm_T(const float (&As)[64][STRA], const float (&BsT)[KD][STRB],
                                           int tx, int ty, float (&acc)[4][4])
{
#pragma unroll 2
  for (int k4 = 0; k4 < KD/4; k4++){
    float a[4][4];
#pragma unroll
    for (int i = 0; i < 4; i++){
      float4 t = *(const float4*)&As[ty*4+i][k4*4];
      a[i][0]=t.x; a[i][1]=t.y; a[i][2]=t.z; a[i][3]=t.w;
    }
#pragma unroll
    for (int e = 0; e < 4; e++){
      float4 b = *(const float4*)&BsT[k4*4+e][tx*4];
#pragma unroll
      for (int i = 0; i < 4; i++){
        acc[i][0] = fmaf(a[i][e], b.x, acc[i][0]);
        acc[i][1] = fmaf(a[i][e], b.y, acc[i][1]);
        acc[i][2] = fmaf(a[i][e], b.z, acc[i][2]);
        acc[i][3] = fmaf(a[i][e], b.w, acc[i][3]);
      }
    }
  }
}

// ---------------- Stage 0: pack W_xp into fragment-ordered bf16 ----------------
// Wf[ph(2)][kc(6)][k32(4)][pt(6)][lane(64)][8]; p = ph*96+pt*16+(lane&15), zero-pad p>=152.
__global__ __launch_bounds__(256) void k_cast_w(
    const float* __restrict__ Wxp, unsigned short* __restrict__ Wf)
{
  int tid = blockIdx.x*256 + threadIdx.x;   // 18432 lane-entries
  if (tid >= 18432) return;
  int lane = tid & 63; int rest = tid >> 6;
  int pt = rest % 6; rest /= 6;
  int k32 = rest & 3; rest >>= 2;
  int kc = rest % 6; int ph = rest / 6;
  int n = lane & 15, q = lane >> 4;
  int p = ph*96 + pt*16 + n;
  int kbase = kc*128 + k32*32 + q*8;
  unsigned short v[8];
#pragma unroll
  for (int j = 0; j < 8; j++)
    v[j] = (p < 152) ? f2b(Wxp[(size_t)p*768 + kbase + j]) : (unsigned short)0;
  *(ushort8*)(Wf + (size_t)tid*8) = *(ushort8*)v;
}

// ---------------- Stage 1: xz = x @ W_in^T + b_in; split -> xx, silu(z) ----------------
__global__ __launch_bounds__(256) void k_gemm_in(
    const float* __restrict__ x, const float* __restrict__ W,
    const float* __restrict__ bias, float* __restrict__ xx, float* __restrict__ zs)
{
  __shared__ float As[64][100];
  __shared__ float BsT[96][68];
  const int m0 = blockIdx.x*64, n0 = blockIdx.y*64;
  const int tid = threadIdx.x;
#pragma unroll
  for (int i = 0; i < 6; i++){
    int idx = tid + i*256;
    { int r = idx/24, c4 = idx%24;
      *(float4*)&As[r][c4*4] = *(const float4*)(x + (size_t)(m0+r)*96 + c4*4); }
    { int r = idx & 63, c4 = idx >> 6;
      float4 wv = *(const float4*)(W + (size_t)(n0+r)*96 + c4*4);
      BsT[c4*4+0][r]=wv.x; BsT[c4*4+1][r]=wv.y; BsT[c4*4+2][r]=wv.z; BsT[c4*4+3][r]=wv.w; }
  }
  __syncthreads();
  const int tx = tid & 15, ty = tid >> 4;
  float acc[4][4] = {};
  micro_mm_T<96,100,68>(As, BsT, tx, ty, acc);
#pragma unroll
  for (int i = 0; i < 4; i++){
    int m = m0 + ty*4 + i;
#pragma unroll
    for (int j = 0; j < 4; j++){
      int n = n0 + tx*4 + j;
      float v = acc[i][j] + bias[n];
      if (n < 192) xx[(size_t)m*192 + n] = v;
      else         zs[(size_t)m*192 + (n-192)] = siluf(v);
    }
  }
}

// ---------------- Stage 2: depthwise 3x3 conv + silu; fp32 xc/xcT + bf16 xcb/xcTb ----------------
__global__ __launch_bounds__(256) void k_conv(
    const float* __restrict__ xx, const float* __restrict__ cw, const float* __restrict__ cb,
    float* __restrict__ xc, float* __restrict__ xcT,
    unsigned short* __restrict__ xcb, unsigned short* __restrict__ xcTb)
{
  int gid = blockIdx.x*256 + threadIdx.x;
  int c = gid % 192;
  int l = (gid/192) & 4095;
  int b = gid / (192*4096);
  int h = l >> 6, w = l & 63;
  float s = 0.f;
#pragma unroll
  for (int kh = 0; kh < 3; kh++){
    int h2 = h + kh - 1;
    if ((unsigned)h2 >= 64u) continue;
#pragma unroll
    for (int kw = 0; kw < 3; kw++){
      int w2 = w + kw - 1;
      if ((unsigned)w2 >= 64u) continue;
      s += xx[((size_t)b*4096 + h2*64 + w2)*192 + c] * cw[c*9 + kh*3 + kw];
    }
  }
  s = siluf(s + cb[c]);
  unsigned short sb = f2b(s);
  size_t i0 = ((size_t)b*4096 + l)*192 + c;
  xc[i0] = s; xcb[i0] = sb;
  int tl = (l & 63)*64 + (l >> 6);
  size_t i1 = ((size_t)b*4096 + tl)*192 + c;
  xcT[i1] = s; xcTb[i1] = sb;
}

// ---------------- Stage 3 (MFMA): x_dbl = W_xp @ concat4(xc views) + b_xp ----------------
// Block 64l x 96p, 4 waves of 32l x 48p. K=768 in 6 slabs of 128 (LDS-staged B frags).
// A frags loaded direct from global bf16 (contiguous 8 channels).
// Output packed x_dbl[b][k][l][48]: dts@0..5, B@8..23, C@24..39.
__global__ __launch_bounds__(256) void k_gemm_xdbl(
    const unsigned short* __restrict__ xcb, const unsigned short* __restrict__ xcTb,
    const unsigned short* __restrict__ Wf, const float* __restrict__ bxp,
    float* __restrict__ xdbl)
{
  __shared__ unsigned short Bsh[4*6*64*8];   // 24 KB
  const int tid = threadIdx.x;
  const int lane = tid & 63, w = tid >> 6;
  const int wl = w & 1, wp = w >> 1;
  const int l0 = blockIdx.x*64, ph = blockIdx.y, b = blockIdx.z;
  const int n = lane & 15, q = lane >> 4;
  f32x4 acc[2][3] = {};
  const unsigned short* slab0 = Wf + (size_t)ph*6*12288;
  for (int kc = 0; kc < 6; kc++){
    __syncthreads();
    const ushort8* srcp = (const ushort8*)(slab0 + (size_t)kc*12288);
#pragma unroll
    for (int t = 0; t < 6; t++) ((ushort8*)Bsh)[tid + t*256] = srcp[tid + t*256];
    __syncthreads();
#pragma unroll
    for (int k32 = 0; k32 < 4; k32++){
      int kk = kc*128 + k32*32;
      int dir = kk/192; int ch = kk%192 + q*8;
      const unsigned short* sp = (dir & 1) ? xcTb : xcb;
      bool rev = (dir >= 2);
      short8 a[2];
#pragma unroll
      for (int mt = 0; mt < 2; mt++){
        int ls = l0 + wl*32 + mt*16 + n;
        int row = rev ? 4095 - ls : ls;
        a[mt] = *(const short8*)(sp + ((size_t)b*4096 + row)*192 + ch);
      }
#pragma unroll
      for (int j = 0; j < 3; j++){
        short8 bfr = *(const short8*)&Bsh[((size_t)(k32*6 + wp*3 + j)*64 + lane)*8];
#pragma unroll
        for (int mt = 0; mt < 2; mt++)
          acc[mt][j] = __builtin_amdgcn_mfma_f32_16x16x32_bf16(a[mt], bfr, acc[mt][j], 0, 0, 0);
      }
    }
  }
#pragma unroll
  for (int mt = 0; mt < 2; mt++)
#pragma unroll
    for (int j = 0; j < 3; j++){
      int p = ph*96 + (wp*3+j)*16 + n;
      if (p < 152){
        int k = p/38, pp = p%38;
        int off = (pp < 6) ? pp : pp + 2;
        float bias = bxp[p];
#pragma unroll
        for (int reg = 0; reg < 4; reg++){
          int l = l0 + wl*32 + mt*16 + q*4 + reg;
          xdbl[(((size_t)b*4 + k)*4096 + l)*48 + off] = acc[mt][j][reg] + bias;
        }
      }
    }
}

// ---------------- Stage 4: dt_eff = softplus(W_dt @ dts + b_dt + dt_bias) ----------------
__global__ __launch_bounds__(256) void k_gemm_dt(
    const float* __restrict__ xdbl, const float* __restrict__ Wdt,
    const float* __restrict__ bdt, const float* __restrict__ dtbias,
    float* __restrict__ dte)
{
  __shared__ float As[64][28];
  __shared__ float BsT[24][68];
  const int m0 = blockIdx.x*64;
  const int n0 = blockIdx.y*64;
  const int b  = blockIdx.z;
  const int tid = threadIdx.x;
#pragma unroll
  for (int i = 0; i < 6; i++){
    int idx = tid + i*256;
    { int r = idx/24, cc = idx%24;
      int kp = cc/6, ri = cc%6;
      As[r][cc] = xdbl[(((size_t)b*4 + kp)*4096 + (m0+r))*48 + ri]; }
    { int r = idx & 63, cc = idx >> 6;
      BsT[cc][r] = Wdt[(size_t)(n0+r)*24 + cc]; }
  }
  __syncthreads();
  const int tx = tid & 15, ty = tid >> 4;
  float acc[4][4] = {};
  micro_mm_T<24,28,68>(As, BsT, tx, ty, acc);
#pragma unroll
  for (int i = 0; i < 4; i++){
    int l = m0 + ty*4 + i;
#pragma unroll
    for (int j = 0; j < 4; j++){
      int c = n0 + tx*4 + j;
      float v = acc[i][j] + bdt[c] + dtbias[c];
      v = (v > 20.f) ? v : log1pf(__expf(v));
      dte[(((size_t)b*4 + c/192)*4096 + l)*192 + (c%192)] = v;
    }
  }
}

// ---------------- Selective scan: lane = channel d, 16 states in-register ----------------
__global__ __launch_bounds__(256) void k_scanA(
    const float* __restrict__ xc, const float* __restrict__ xcT,
    const float* __restrict__ xdbl, const float* __restrict__ dte,
    const float* __restrict__ A_log,
    float* __restrict__ Pb, float* __restrict__ Sb)
{
  const int lane = threadIdx.x & 63;
  const int wid  = blockIdx.x*4 + (threadIdx.x >> 6);
  const int ck = wid & (NCK-1); const int g = wid / NCK;
  const int dblk = g % 3; const int bk = g / 3;
  const int k = bk & 3; const int b = bk >> 2;
  const int d = dblk*64 + lane; const int ch = k*192 + d;
  float An[16];
  {
    const float4* ap = (const float4*)(A_log + (size_t)ch*16);
#pragma unroll
    for (int i = 0; i < 4; i++){
      float4 t = ap[i];
      An[4*i+0] = -__expf(t.x); An[4*i+1] = -__expf(t.y);
      An[4*i+2] = -__expf(t.z); An[4*i+3] = -__expf(t.w);
    }
  }
  const int l0 = ck*CHUNK;
  const bool rev = (k >= 2);
  const float* srcb = (k & 1) ? xcT : xc;
  const float* dtp = dte  + (((size_t)b*4 + k)*4096 + l0)*192 + d;
  const float* xdp = xdbl + (((size_t)b*4 + k)*4096 + l0)*48;
  const float* up  = srcb + ((size_t)b*4096 + (rev ? 4095 - l0 : l0))*192 + d;
  const int ust = rev ? -192 : 192;
  float h[16];
#pragma unroll
  for (int n = 0; n < 16; n++) h[n] = 0.f;
  float sdt = 0.f;
#pragma unroll 2
  for (int t = 0; t < CHUNK; t++){
    float dt = dtp[0];
    float u  = up[0];
    float4 B0 = *(const float4*)(xdp + 8);
    float4 B1 = *(const float4*)(xdp + 12);
    float4 B2 = *(const float4*)(xdp + 16);
    float4 B3 = *(const float4*)(xdp + 20);
    float Bv[16] = {B0.x,B0.y,B0.z,B0.w, B1.x,B1.y,B1.z,B1.w,
                    B2.x,B2.y,B2.z,B2.w, B3.x,B3.y,B3.z,B3.w};
    float dtu = dt*u;
    sdt += dt;
#pragma unroll
    for (int n = 0; n < 16; n++){
      float dA = __expf(dt*An[n]);
      h[n] = fmaf(dA, h[n], dtu*Bv[n]);
    }
    dtp += 192; xdp += 48; up += ust;
  }
  size_t base = ((size_t)wid*16)*64 + lane;
#pragma unroll
  for (int n = 0; n < 16; n++){
    Pb[base + n*64] = __expf(An[n]*sdt);
    Sb[base + n*64] = h[n];
  }
}

__global__ __launch_bounds__(256) void k_scanB(
    const float* __restrict__ Pb, const float* __restrict__ Sb, float* __restrict__ H0)
{
  int tid = blockIdx.x*256 + threadIdx.x;  // 24576 = 24 groups * 16 n * 64 lanes
  int lane = tid & 63; int n = (tid >> 6) & 15; int g = tid >> 10;
  float h = 0.f;
  for (int ck = 0; ck < NCK; ck++){
    size_t idx = (((size_t)(g*NCK + ck)*16) + n)*64 + lane;
    H0[idx] = h;
    h = fmaf(Pb[idx], h, Sb[idx]);
  }
}

__global__ __launch_bounds__(256) void k_scanC(
    const float* __restrict__ xc, const float* __restrict__ xcT,
    const float* __restrict__ xdbl, const float* __restrict__ dte,
    const float* __restrict__ A_log, const float* __restrict__ Dskip,
    const float* __restrict__ H0, float* __restrict__ ys)
{
  const int lane = threadIdx.x & 63;
  const int wid  = blockIdx.x*4 + (threadIdx.x >> 6);
  const int ck = wid & (NCK-1); const int g = wid / NCK;
  const int dblk = g % 3; const int bk = g / 3;
  const int k = bk & 3; const int b = bk >> 2;
  const int d = dblk*64 + lane; const int ch = k*192 + d;
  float An[16];
  {
    const float4* ap = (const float4*)(A_log + (size_t)ch*16);
#pragma unroll
    for (int i = 0; i < 4; i++){
      float4 t = ap[i];
      An[4*i+0] = -__expf(t.x); An[4*i+1] = -__expf(t.y);
      An[4*i+2] = -__expf(t.z); An[4*i+3] = -__expf(t.w);
    }
  }
  const float Dv = Dskip[ch];
  const int l0 = ck*CHUNK;
  const bool rev = (k >= 2);
  const float* srcb = (k & 1) ? xcT : xc;
  const float* dtp = dte  + (((size_t)b*4 + k)*4096 + l0)*192 + d;
  const float* xdp = xdbl + (((size_t)b*4 + k)*4096 + l0)*48;
  const float* up  = srcb + ((size_t)b*4096 + (rev ? 4095 - l0 : l0))*192 + d;
  const int ust = rev ? -192 : 192;
  float* ysb = ys + ((size_t)(k*2 + b))*4096*192 + d;
  float h[16];
  size_t base = ((size_t)wid*16)*64 + lane;
#pragma unroll
  for (int n = 0; n < 16; n++) h[n] = H0[base + n*64];
#pragma unroll 2
  for (int t = 0; t < CHUNK; t++){
    int l = l0 + t;
    float dt = dtp[0];
    float u  = up[0];
    float4 B0 = *(const float4*)(xdp + 8);
    float4 B1 = *(const float4*)(xdp + 12);
    float4 B2 = *(const float4*)(xdp + 16);
    float4 B3 = *(const float4*)(xdp + 20);
    float4 C0 = *(const float4*)(xdp + 24);
    float4 C1 = *(const float4*)(xdp + 28);
    float4 C2 = *(const float4*)(xdp + 32);
    float4 C3 = *(const float4*)(xdp + 36);
    float Bv[16] = {B0.x,B0.y,B0.z,B0.w, B1.x,B1.y,B1.z,B1.w,
                    B2.x,B2.y,B2.z,B2.w, B3.x,B3.y,B3.z,B3.w};
    float Cv[16] = {C0.x,C0.y,C0.z,C0.w, C1.x,C1.y,C1.z,C1.w,
                    C2.x,C2.y,C2.z,C2.w, C3.x,C3.y,C3.z,C3.w};
    float dtu = dt*u;
    float y = u*Dv;
#pragma unroll
    for (int n = 0; n < 16; n++){
      float dA = __expf(dt*An[n]);
      h[n] = fmaf(dA, h[n], dtu*Bv[n]);
      y = fmaf(h[n], Cv[n], y);
    }
    int pos;
    if (k == 0)      pos = l;
    else if (k == 1) pos = (l & 63)*64 + (l >> 6);
    else { int l2 = 4095 - l; pos = (k == 2) ? l2 : ((l2 & 63)*64 + (l2 >> 6)); }
    ysb[(size_t)pos*192] = y;
    dtp += 192; xdp += 48; up += ust;
  }
}

// ---------------- Stage 6: merge 4 planes + LayerNorm * silu(z) ----------------
__global__ __launch_bounds__(256) void k_ln(
    const float* __restrict__ ys, const float* __restrict__ zs,
    const float* __restrict__ gamma, const float* __restrict__ beta,
    float* __restrict__ yln)
{
  int row = blockIdx.x*4 + (threadIdx.x >> 6);
  int lane = threadIdx.x & 63;
  int b = row >> 12; int l = row & 4095;
  float v[3];
#pragma unroll
  for (int j = 0; j < 3; j++){
    int c = lane + j*64;
    float s = 0.f;
#pragma unroll
    for (int k = 0; k < 4; k++) s += ys[(((size_t)k*2 + b)*4096 + l)*192 + c];
    v[j] = s;
  }
  float tot = v[0] + v[1] + v[2];
#pragma unroll
  for (int o = 1; o < 64; o <<= 1) tot += __shfl_xor(tot, o);
  float mean = tot * (1.f/192.f);
  float d0 = v[0]-mean, d1 = v[1]-mean, d2 = v[2]-mean;
  float vs = d0*d0 + d1*d1 + d2*d2;
#pragma unroll
  for (int o = 1; o < 64; o <<= 1) vs += __shfl_xor(vs, o);
  float rstd = rsqrtf(vs*(1.f/192.f) + 1e-5f);
  float nd[3] = {d0, d1, d2};
#pragma unroll
  for (int j = 0; j < 3; j++){
    int c = lane + j*64;
    float val = nd[j]*rstd*gamma[c] + beta[c];
    val *= zs[(size_t)row*192 + c];
    yln[(size_t)row*192 + c] = val;
  }
}

// ---------------- Stage 7: out = y_ln @ W_out^T + b_out ----------------
__global__ __launch_bounds__(256) void k_gemm_out(
    const float* __restrict__ yln, const float* __restrict__ Wout,
    const float* __restrict__ bout, float* __restrict__ out)
{
  __shared__ float As[64][100];
  __shared__ float BsT[96][68];
  const int m0 = blockIdx.x*64, n0 = blockIdx.y*64;
  const int tid = threadIdx.x;
  const int tx = tid & 15, ty = tid >> 4;
  float acc[4][4] = {};
  for (int kc = 0; kc < 2; kc++){
    __syncthreads();
#pragma unroll
    for (int i = 0; i < 6; i++){
      int idx = tid + i*256;
      { int r = idx/24, c4 = idx%24;
        *(float4*)&As[r][c4*4] = *(const float4*)(yln + (size_t)(m0+r)*192 + kc*96 + c4*4); }
      { int r = idx & 63, c4 = idx >> 6;
        int nn = n0 + r;
        float4 wv = make_float4(0.f,0.f,0.f,0.f);
        if (nn < 96) wv = *(const float4*)(Wout + (size_t)nn*192 + kc*96 + c4*4);
        BsT[c4*4+0][r]=wv.x; BsT[c4*4+1][r]=wv.y; BsT[c4*4+2][r]=wv.z; BsT[c4*4+3][r]=wv.w; }
    }
    __syncthreads();
    micro_mm_T<96,100,68>(As, BsT, tx, ty, acc);
  }
#pragma unroll
  for (int i = 0; i < 4; i++){
    int m = m0 + ty*4 + i;
#pragma unroll
    for (int j = 0; j < 4; j++){
      int n = n0 + tx*4 + j;
      if (n < 96) out[(size_t)m*96 + n] = acc[i][j] + bout[n];
    }
  }
}

extern "C" void kernel_launch(void* const* d_in, const int* in_sizes, int n_in,
                              void* d_out, int out_size, void* d_ws, size_t ws_size,
                              hipStream_t stream)
{
  const float* x      = (const float*)d_in[0];
  const float* W_in   = (const float*)d_in[1];
  const float* b_in   = (const float*)d_in[2];
  const float* conv_w = (const float*)d_in[3];
  const float* conv_b = (const float*)d_in[4];
  const float* W_xp   = (const float*)d_in[5];
  const float* b_xp   = (const float*)d_in[6];
  const float* W_dt   = (const float*)d_in[7];
  const float* b_dt   = (const float*)d_in[8];
  const float* A_log  = (const float*)d_in[9];
  const float* D_skip = (const float*)d_in[10];
  const float* dt_bias= (const float*)d_in[11];
  const float* W_out  = (const float*)d_in[12];
  const float* b_out  = (const float*)d_in[13];
  const float* gamma  = (const float*)d_in[14];
  const float* beta   = (const float*)d_in[15];
  float* out = (float*)d_out;

  float* ws   = (float*)d_ws;
  float* xx   = ws;               // 1572864 (dead after conv -> Pb)
  float* zs   = xx  + 1572864;    // 1572864
  float* xc   = zs  + 1572864;    // 1572864
  float* xcT  = xc  + 1572864;    // 1572864
  float* xdbl = xcT + 1572864;    // 2*4*4096*48 = 1572864
  float* dte  = xdbl+ 1572864;    // 6291456
  float* ysb  = dte + 6291456;    // 6291456
  float* yln  = ysb + 6291456;    // 1572864
  float* H0   = yln + 1572864;    // 1572864  -> total 23592960 floats (94.4MB)
  float* Pb   = xx;               // alias (xx dead after conv)
  float* Sb   = yln;              // alias (yln written only at ln)
  unsigned short* xcb  = (unsigned short*)ysb;          // 1572864 bf16 (dead once scanC writes ysb)
  unsigned short* xcTb = xcb + 1572864;                 // 1572864 bf16
  unsigned short* Wf   = (unsigned short*)H0;           // 294912 bf16 (dead once scanB writes H0)

  k_cast_w   <<<72,              256, 0, stream>>>(W_xp, Wf);
  k_gemm_in  <<<dim3(128, 6),    256, 0, stream>>>(x, W_in, b_in, xx, zs);
  k_conv     <<<6144,            256, 0, stream>>>(xx, conv_w, conv_b, xc, xcT, xcb, xcTb);
  k_gemm_xdbl<<<dim3(64, 2, 2),  256, 0, stream>>>(xcb, xcTb, Wf, b_xp, xdbl);
  k_gemm_dt  <<<dim3(64, 12, 2), 256, 0, stream>>>(xdbl, W_dt, b_dt, dt_bias, dte);
  k_scanA    <<<384,             256, 0, stream>>>(xc, xcT, xdbl, dte, A_log, Pb, Sb);
  k_scanB    <<<96,              256, 0, stream>>>(Pb, Sb, H0);
  k_scanC    <<<384,             256, 0, stream>>>(xc, xcT, xdbl, dte, A_log, D_skip, H0, ysb);
  k_ln       <<<2048,            256, 0, stream>>>(ysb, zs, gamma, beta, yln);
  k_gemm_out <<<dim3(128, 2),    256, 0, stream>>>(yln, W_out, b_out, out);
}

// Round 5
// 238.423 us; speedup vs baseline: 2.7376x; 1.1791x over previous
//
#include <hip/hip_runtime.h>
#include <cstdint>
#include <cstddef>

// SS2D: B=2, H=W=64 (L=4096), D_MODEL=96, D_INNER=192, K=4 dirs, N=16 states, DT_RANK=6.
// R1: GEMMs: limited unroll (no spills), transposed B tile in LDS (no bank conflicts).
// R2: scan: lane = channel, 16 states in-register, no shuffles; x_dbl packed stride 48.
// R3: k_gemm_xdbl -> bf16 MFMA 16x16x32; W_xp pre-packed fragment-order bf16.
// R4: scan latency attack: CHUNK 64->32 (12 waves/CU), exp2-folded A (v_exp_f32 direct),
//     readfirstlane(wid) to promote uniform B/C loads to scalar path.
//     ws re-aliased: 88.1 MB total (Sb/H0 share [xx][yln]; Pb/xcb/xcTb/Wf inside ysb).

#define CHUNK 32
#define NCK   128   // 4096 / CHUNK

#if __has_builtin(__builtin_amdgcn_exp2f)
#define EXP2(x) __builtin_amdgcn_exp2f(x)
#else
#define EXP2(x) exp2f(x)
#endif
#define LOG2E 1.44269504088896340736f

typedef __attribute__((ext_vector_type(8))) short short8;
typedef __attribute__((ext_vector_type(8))) unsigned short ushort8;
typedef __attribute__((ext_vector_type(4))) float f32x4;

__device__ __forceinline__ float siluf(float x){ return x * (1.f/(1.f+__expf(-x))); }
__device__ __forceinline__ unsigned short f2b(float f){
  uint32_t u = __float_as_uint(f);
  uint32_t r = (u + 0x7fffu + ((u>>16)&1u)) >> 16;
  return (unsigned short)r;
}

template<int KD, int STRA, int STRB>
__device__ __forceinline__ void micro_mm_T(const float (&As)[64][STRA], const float (&BsT)[KD][STRB],
                                           int tx, int ty, float (&acc)[4][4])
{
#pragma unroll 2
  for (int k4 = 0; k4 < KD/4; k4++){
    float a[4][4];
#pragma unroll
    for (int i = 0; i < 4; i++){
      float4 t = *(const float4*)&As[ty*4+i][k4*4];
      a[i][0]=t.x; a[i][1]=t.y; a[i][2]=t.z; a[i][3]=t.w;
    }
#pragma unroll
    for (int e = 0; e < 4; e++){
      float4 b = *(const float4*)&BsT[k4*4+e][tx*4];
#pragma unroll
      for (int i = 0; i < 4; i++){
        acc[i][0] = fmaf(a[i][e], b.x, acc[i][0]);
        acc[i][1] = fmaf(a[i][e], b.y, acc[i][1]);
        acc[i][2] = fmaf(a[i][e], b.z, acc[i][2]);
        acc[i][3] = fmaf(a[i][e], b.w, acc[i][3]);
      }
    }
  }
}

// ---------------- Stage 0: pack W_xp into fragment-ordered bf16 ----------------
__global__ __launch_bounds__(256) void k_cast_w(
    const float* __restrict__ Wxp, unsigned short* __restrict__ Wf)
{
  int tid = blockIdx.x*256 + threadIdx.x;   // 18432 lane-entries
  if (tid >= 18432) return;
  int lane = tid & 63; int rest = tid >> 6;
  int pt = rest % 6; rest /= 6;
  int k32 = rest & 3; rest >>= 2;
  int kc = rest % 6; int ph = rest / 6;
  int n = lane & 15, q = lane >> 4;
  int p = ph*96 + pt*16 + n;
  int kbase = kc*128 + k32*32 + q*8;
  unsigned short v[8];
#pragma unroll
  for (int j = 0; j < 8; j++)
    v[j] = (p < 152) ? f2b(Wxp[(size_t)p*768 + kbase + j]) : (unsigned short)0;
  *(ushort8*)(Wf + (size_t)tid*8) = *(ushort8*)v;
}

// ---------------- Stage 1: xz = x @ W_in^T + b_in; split -> xx, silu(z) ----------------
__global__ __launch_bounds__(256) void k_gemm_in(
    const float* __restrict__ x, const float* __restrict__ W,
    const float* __restrict__ bias, float* __restrict__ xx, float* __restrict__ zs)
{
  __shared__ float As[64][100];
  __shared__ float BsT[96][68];
  const int m0 = blockIdx.x*64, n0 = blockIdx.y*64;
  const int tid = threadIdx.x;
#pragma unroll
  for (int i = 0; i < 6; i++){
    int idx = tid + i*256;
    { int r = idx/24, c4 = idx%24;
      *(float4*)&As[r][c4*4] = *(const float4*)(x + (size_t)(m0+r)*96 + c4*4); }
    { int r = idx & 63, c4 = idx >> 6;
      float4 wv = *(const float4*)(W + (size_t)(n0+r)*96 + c4*4);
      BsT[c4*4+0][r]=wv.x; BsT[c4*4+1][r]=wv.y; BsT[c4*4+2][r]=wv.z; BsT[c4*4+3][r]=wv.w; }
  }
  __syncthreads();
  const int tx = tid & 15, ty = tid >> 4;
  float acc[4][4] = {};
  micro_mm_T<96,100,68>(As, BsT, tx, ty, acc);
#pragma unroll
  for (int i = 0; i < 4; i++){
    int m = m0 + ty*4 + i;
#pragma unroll
    for (int j = 0; j < 4; j++){
      int n = n0 + tx*4 + j;
      float v = acc[i][j] + bias[n];
      if (n < 192) xx[(size_t)m*192 + n] = v;
      else         zs[(size_t)m*192 + (n-192)] = siluf(v);
    }
  }
}

// ---------------- Stage 2: depthwise 3x3 conv + silu; fp32 xc/xcT + bf16 xcb/xcTb ----------------
__global__ __launch_bounds__(256) void k_conv(
    const float* __restrict__ xx, const float* __restrict__ cw, const float* __restrict__ cb,
    float* __restrict__ xc, float* __restrict__ xcT,
    unsigned short* __restrict__ xcb, unsigned short* __restrict__ xcTb)
{
  int gid = blockIdx.x*256 + threadIdx.x;
  int c = gid % 192;
  int l = (gid/192) & 4095;
  int b = gid / (192*4096);
  int h = l >> 6, w = l & 63;
  float s = 0.f;
#pragma unroll
  for (int kh = 0; kh < 3; kh++){
    int h2 = h + kh - 1;
    if ((unsigned)h2 >= 64u) continue;
#pragma unroll
    for (int kw = 0; kw < 3; kw++){
      int w2 = w + kw - 1;
      if ((unsigned)w2 >= 64u) continue;
      s += xx[((size_t)b*4096 + h2*64 + w2)*192 + c] * cw[c*9 + kh*3 + kw];
    }
  }
  s = siluf(s + cb[c]);
  unsigned short sb = f2b(s);
  size_t i0 = ((size_t)b*4096 + l)*192 + c;
  xc[i0] = s; xcb[i0] = sb;
  int tl = (l & 63)*64 + (l >> 6);
  size_t i1 = ((size_t)b*4096 + tl)*192 + c;
  xcT[i1] = s; xcTb[i1] = sb;
}

// ---------------- Stage 3 (MFMA): x_dbl = W_xp @ concat4(xc views) + b_xp ----------------
__global__ __launch_bounds__(256) void k_gemm_xdbl(
    const unsigned short* __restrict__ xcb, const unsigned short* __restrict__ xcTb,
    const unsigned short* __restrict__ Wf, const float* __restrict__ bxp,
    float* __restrict__ xdbl)
{
  __shared__ unsigned short Bsh[4*6*64*8];   // 24 KB
  const int tid = threadIdx.x;
  const int lane = tid & 63, w = tid >> 6;
  const int wl = w & 1, wp = w >> 1;
  const int l0 = blockIdx.x*64, ph = blockIdx.y, b = blockIdx.z;
  const int n = lane & 15, q = lane >> 4;
  f32x4 acc[2][3] = {};
  const unsigned short* slab0 = Wf + (size_t)ph*6*12288;
  for (int kc = 0; kc < 6; kc++){
    __syncthreads();
    const ushort8* srcp = (const ushort8*)(slab0 + (size_t)kc*12288);
#pragma unroll
    for (int t = 0; t < 6; t++) ((ushort8*)Bsh)[tid + t*256] = srcp[tid + t*256];
    __syncthreads();
#pragma unroll
    for (int k32 = 0; k32 < 4; k32++){
      int kk = kc*128 + k32*32;
      int dir = kk/192; int ch = kk%192 + q*8;
      const unsigned short* sp = (dir & 1) ? xcTb : xcb;
      bool rev = (dir >= 2);
      short8 a[2];
#pragma unroll
      for (int mt = 0; mt < 2; mt++){
        int ls = l0 + wl*32 + mt*16 + n;
        int row = rev ? 4095 - ls : ls;
        a[mt] = *(const short8*)(sp + ((size_t)b*4096 + row)*192 + ch);
      }
#pragma unroll
      for (int j = 0; j < 3; j++){
        short8 bfr = *(const short8*)&Bsh[((size_t)(k32*6 + wp*3 + j)*64 + lane)*8];
#pragma unroll
        for (int mt = 0; mt < 2; mt++)
          acc[mt][j] = __builtin_amdgcn_mfma_f32_16x16x32_bf16(a[mt], bfr, acc[mt][j], 0, 0, 0);
      }
    }
  }
#pragma unroll
  for (int mt = 0; mt < 2; mt++)
#pragma unroll
    for (int j = 0; j < 3; j++){
      int p = ph*96 + (wp*3+j)*16 + n;
      if (p < 152){
        int k = p/38, pp = p%38;
        int off = (pp < 6) ? pp : pp + 2;
        float bias = bxp[p];
#pragma unroll
        for (int reg = 0; reg < 4; reg++){
          int l = l0 + wl*32 + mt*16 + q*4 + reg;
          xdbl[(((size_t)b*4 + k)*4096 + l)*48 + off] = acc[mt][j][reg] + bias;
        }
      }
    }
}

// ---------------- Stage 4: dt_eff = softplus(W_dt @ dts + b_dt + dt_bias) ----------------
__global__ __launch_bounds__(256) void k_gemm_dt(
    const float* __restrict__ xdbl, const float* __restrict__ Wdt,
    const float* __restrict__ bdt, const float* __restrict__ dtbias,
    float* __restrict__ dte)
{
  __shared__ float As[64][28];
  __shared__ float BsT[24][68];
  const int m0 = blockIdx.x*64;
  const int n0 = blockIdx.y*64;
  const int b  = blockIdx.z;
  const int tid = threadIdx.x;
#pragma unroll
  for (int i = 0; i < 6; i++){
    int idx = tid + i*256;
    { int r = idx/24, cc = idx%24;
      int kp = cc/6, ri = cc%6;
      As[r][cc] = xdbl[(((size_t)b*4 + kp)*4096 + (m0+r))*48 + ri]; }
    { int r = idx & 63, cc = idx >> 6;
      BsT[cc][r] = Wdt[(size_t)(n0+r)*24 + cc]; }
  }
  __syncthreads();
  const int tx = tid & 15, ty = tid >> 4;
  float acc[4][4] = {};
  micro_mm_T<24,28,68>(As, BsT, tx, ty, acc);
#pragma unroll
  for (int i = 0; i < 4; i++){
    int l = m0 + ty*4 + i;
#pragma unroll
    for (int j = 0; j < 4; j++){
      int c = n0 + tx*4 + j;
      float v = acc[i][j] + bdt[c] + dtbias[c];
      v = (v > 20.f) ? v : log1pf(__expf(v));
      dte[(((size_t)b*4 + c/192)*4096 + l)*192 + (c%192)] = v;
    }
  }
}

// ---------------- Selective scan: lane = channel d, 16 states in-register ----------------
// wave: 64 lanes = 64 contiguous channels. group g = (b,k,dblk): 24 groups.
// wid = g*NCK + ck; 3072 waves, 4/block -> 768 blocks.
__global__ __launch_bounds__(256) void k_scanA(
    const float* __restrict__ xc, const float* __restrict__ xcT,
    const float* __restrict__ xdbl, const float* __restrict__ dte,
    const float* __restrict__ A_log,
    float* __restrict__ Pb, float* __restrict__ Sb)
{
  const int lane = threadIdx.x & 63;
  const int wid  = __builtin_amdgcn_readfirstlane(blockIdx.x*4 + (threadIdx.x >> 6));
  const int ck = wid & (NCK-1); const int g = wid / NCK;
  const int dblk = g % 3; const int bk = g / 3;
  const int k = bk & 3; const int b = bk >> 2;
  const int d = dblk*64 + lane; const int ch = k*192 + d;
  float An[16];  // -exp(A_log)*log2e
  {
    const float4* ap = (const float4*)(A_log + (size_t)ch*16);
#pragma unroll
    for (int i = 0; i < 4; i++){
      float4 t = ap[i];
      An[4*i+0] = -LOG2E*__expf(t.x); An[4*i+1] = -LOG2E*__expf(t.y);
      An[4*i+2] = -LOG2E*__expf(t.z); An[4*i+3] = -LOG2E*__expf(t.w);
    }
  }
  const int l0 = ck*CHUNK;
  const bool rev = (k >= 2);
  const float* srcb = (k & 1) ? xcT : xc;
  const float* dtp = dte  + (((size_t)b*4 + k)*4096 + l0)*192 + d;
  const float* xdp = xdbl + (((size_t)b*4 + k)*4096 + l0)*48;
  const float* up  = srcb + ((size_t)b*4096 + (rev ? 4095 - l0 : l0))*192 + d;
  const int ust = rev ? -192 : 192;
  float h[16];
#pragma unroll
  for (int n = 0; n < 16; n++) h[n] = 0.f;
  float sdt = 0.f;
#pragma unroll 2
  for (int t = 0; t < CHUNK; t++){
    float dt = dtp[0];
    float u  = up[0];
    float4 B0 = *(const float4*)(xdp + 8);
    float4 B1 = *(const float4*)(xdp + 12);
    float4 B2 = *(const float4*)(xdp + 16);
    float4 B3 = *(const float4*)(xdp + 20);
    float Bv[16] = {B0.x,B0.y,B0.z,B0.w, B1.x,B1.y,B1.z,B1.w,
                    B2.x,B2.y,B2.z,B2.w, B3.x,B3.y,B3.z,B3.w};
    float dtu = dt*u;
    sdt += dt;
#pragma unroll
    for (int n = 0; n < 16; n++){
      float dA = EXP2(dt*An[n]);
      h[n] = fmaf(dA, h[n], dtu*Bv[n]);
    }
    dtp += 192; xdp += 48; up += ust;
  }
  size_t base = ((size_t)wid*16)*64 + lane;
#pragma unroll
  for (int n = 0; n < 16; n++){
    Pb[base + n*64] = EXP2(An[n]*sdt);
    Sb[base + n*64] = h[n];
  }
}

// SbH0: Sb and H0 share this buffer (same idx; read Sb before writing H0). No __restrict__!
__global__ __launch_bounds__(256) void k_scanB(
    const float* __restrict__ Pb, float* SbH0)
{
  int tid = blockIdx.x*256 + threadIdx.x;  // 24576 = 24 groups * 16 n * 64 lanes
  int lane = tid & 63; int n = (tid >> 6) & 15; int g = tid >> 10;
  float h = 0.f;
  for (int ck = 0; ck < NCK; ck++){
    size_t idx = (((size_t)(g*NCK + ck)*16) + n)*64 + lane;
    float p = Pb[idx];
    float s = SbH0[idx];
    SbH0[idx] = h;
    h = fmaf(p, h, s);
  }
}

__global__ __launch_bounds__(256) void k_scanC(
    const float* __restrict__ xc, const float* __restrict__ xcT,
    const float* __restrict__ xdbl, const float* __restrict__ dte,
    const float* __restrict__ A_log, const float* __restrict__ Dskip,
    const float* __restrict__ H0, float* __restrict__ ys)
{
  const int lane = threadIdx.x & 63;
  const int wid  = __builtin_amdgcn_readfirstlane(blockIdx.x*4 + (threadIdx.x >> 6));
  const int ck = wid & (NCK-1); const int g = wid / NCK;
  const int dblk = g % 3; const int bk = g / 3;
  const int k = bk & 3; const int b = bk >> 2;
  const int d = dblk*64 + lane; const int ch = k*192 + d;
  float An[16];  // -exp(A_log)*log2e
  {
    const float4* ap = (const float4*)(A_log + (size_t)ch*16);
#pragma unroll
    for (int i = 0; i < 4; i++){
      float4 t = ap[i];
      An[4*i+0] = -LOG2E*__expf(t.x); An[4*i+1] = -LOG2E*__expf(t.y);
      An[4*i+2] = -LOG2E*__expf(t.z); An[4*i+3] = -LOG2E*__expf(t.w);
    }
  }
  const float Dv = Dskip[ch];
  const int l0 = ck*CHUNK;
  const bool rev = (k >= 2);
  const float* srcb = (k & 1) ? xcT : xc;
  const float* dtp = dte  + (((size_t)b*4 + k)*4096 + l0)*192 + d;
  const float* xdp = xdbl + (((size_t)b*4 + k)*4096 + l0)*48;
  const float* up  = srcb + ((size_t)b*4096 + (rev ? 4095 - l0 : l0))*192 + d;
  const int ust = rev ? -192 : 192;
  float* ysb = ys + ((size_t)(k*2 + b))*4096*192 + d;
  float h[16];
  size_t base = ((size_t)wid*16)*64 + lane;
#pragma unroll
  for (int n = 0; n < 16; n++) h[n] = H0[base + n*64];
#pragma unroll 2
  for (int t = 0; t < CHUNK; t++){
    int l = l0 + t;
    float dt = dtp[0];
    float u  = up[0];
    float4 B0 = *(const float4*)(xdp + 8);
    float4 B1 = *(const float4*)(xdp + 12);
    float4 B2 = *(const float4*)(xdp + 16);
    float4 B3 = *(const float4*)(xdp + 20);
    float4 C0 = *(const float4*)(xdp + 24);
    float4 C1 = *(const float4*)(xdp + 28);
    float4 C2 = *(const float4*)(xdp + 32);
    float4 C3 = *(const float4*)(xdp + 36);
    float Bv[16] = {B0.x,B0.y,B0.z,B0.w, B1.x,B1.y,B1.z,B1.w,
                    B2.x,B2.y,B2.z,B2.w, B3.x,B3.y,B3.z,B3.w};
    float Cv[16] = {C0.x,C0.y,C0.z,C0.w, C1.x,C1.y,C1.z,C1.w,
                    C2.x,C2.y,C2.z,C2.w, C3.x,C3.y,C3.z,C3.w};
    float dtu = dt*u;
    float y = u*Dv;
#pragma unroll
    for (int n = 0; n < 16; n++){
      float dA = EXP2(dt*An[n]);
      h[n] = fmaf(dA, h[n], dtu*Bv[n]);
      y = fmaf(h[n], Cv[n], y);
    }
    int pos;
    if (k == 0)      pos = l;
    else if (k == 1) pos = (l & 63)*64 + (l >> 6);
    else { int l2 = 4095 - l; pos = (k == 2) ? l2 : ((l2 & 63)*64 + (l2 >> 6)); }
    ysb[(size_t)pos*192] = y;
    dtp += 192; xdp += 48; up += ust;
  }
}

// ---------------- Stage 6: merge 4 planes + LayerNorm * silu(z) ----------------
__global__ __launch_bounds__(256) void k_ln(
    const float* __restrict__ ys, const float* __restrict__ zs,
    const float* __restrict__ gamma, const float* __restrict__ beta,
    float* __restrict__ yln)
{
  int row = blockIdx.x*4 + (threadIdx.x >> 6);
  int lane = threadIdx.x & 63;
  int b = row >> 12; int l = row & 4095;
  float v[3];
#pragma unroll
  for (int j = 0; j < 3; j++){
    int c = lane + j*64;
    float s = 0.f;
#pragma unroll
    for (int k = 0; k < 4; k++) s += ys[(((size_t)k*2 + b)*4096 + l)*192 + c];
    v[j] = s;
  }
  float tot = v[0] + v[1] + v[2];
#pragma unroll
  for (int o = 1; o < 64; o <<= 1) tot += __shfl_xor(tot, o);
  float mean = tot * (1.f/192.f);
  float d0 = v[0]-mean, d1 = v[1]-mean, d2 = v[2]-mean;
  float vs = d0*d0 + d1*d1 + d2*d2;
#pragma unroll
  for (int o = 1; o < 64; o <<= 1) vs += __shfl_xor(vs, o);
  float rstd = rsqrtf(vs*(1.f/192.f) + 1e-5f);
  float nd[3] = {d0, d1, d2};
#pragma unroll
  for (int j = 0; j < 3; j++){
    int c = lane + j*64;
    float val = nd[j]*rstd*gamma[c] + beta[c];
    val *= zs[(size_t)row*192 + c];
    yln[(size_t)row*192 + c] = val;
  }
}

// ---------------- Stage 7: out = y_ln @ W_out^T + b_out ----------------
__global__ __launch_bounds__(256) void k_gemm_out(
    const float* __restrict__ yln, const float* __restrict__ Wout,
    const float* __restrict__ bout, float* __restrict__ out)
{
  __shared__ float As[64][100];
  __shared__ float BsT[96][68];
  const int m0 = blockIdx.x*64, n0 = blockIdx.y*64;
  const int tid = threadIdx.x;
  const int tx = tid & 15, ty = tid >> 4;
  float acc[4][4] = {};
  for (int kc = 0; kc < 2; kc++){
    __syncthreads();
#pragma unroll
    for (int i = 0; i < 6; i++){
      int idx = tid + i*256;
      { int r = idx/24, c4 = idx%24;
        *(float4*)&As[r][c4*4] = *(const float4*)(yln + (size_t)(m0+r)*192 + kc*96 + c4*4); }
      { int r = idx & 63, c4 = idx >> 6;
        int nn = n0 + r;
        float4 wv = make_float4(0.f,0.f,0.f,0.f);
        if (nn < 96) wv = *(const float4*)(Wout + (size_t)nn*192 + kc*96 + c4*4);
        BsT[c4*4+0][r]=wv.x; BsT[c4*4+1][r]=wv.y; BsT[c4*4+2][r]=wv.z; BsT[c4*4+3][r]=wv.w; }
    }
    __syncthreads();
    micro_mm_T<96,100,68>(As, BsT, tx, ty, acc);
  }
#pragma unroll
  for (int i = 0; i < 4; i++){
    int m = m0 + ty*4 + i;
#pragma unroll
    for (int j = 0; j < 4; j++){
      int n = n0 + tx*4 + j;
      if (n < 96) out[(size_t)m*96 + n] = acc[i][j] + bout[n];
    }
  }
}

extern "C" void kernel_launch(void* const* d_in, const int* in_sizes, int n_in,
                              void* d_out, int out_size, void* d_ws, size_t ws_size,
                              hipStream_t stream)
{
  const float* x      = (const float*)d_in[0];
  const float* W_in   = (const float*)d_in[1];
  const float* b_in   = (const float*)d_in[2];
  const float* conv_w = (const float*)d_in[3];
  const float* conv_b = (const float*)d_in[4];
  const float* W_xp   = (const float*)d_in[5];
  const float* b_xp   = (const float*)d_in[6];
  const float* W_dt   = (const float*)d_in[7];
  const float* b_dt   = (const float*)d_in[8];
  const float* A_log  = (const float*)d_in[9];
  const float* D_skip = (const float*)d_in[10];
  const float* dt_bias= (const float*)d_in[11];
  const float* W_out  = (const float*)d_in[12];
  const float* b_out  = (const float*)d_in[13];
  const float* gamma  = (const float*)d_in[14];
  const float* beta   = (const float*)d_in[15];
  float* out = (float*)d_out;

  // Layout (floats). Total 22020096 floats = 88.1 MB.
  float* ws   = (float*)d_ws;
  float* xx   = ws;               // @0        1572864 (gemm_in->conv; then SbH0 part 1)
  float* yln  = ws + 1572864;     // @1572864  1572864 (SbH0 part 2; ln->gemm_out)
  float* zs   = ws + 3145728;     // 1572864 (gemm_in->ln)
  float* xc   = ws + 4718592;     // 1572864
  float* xcT  = ws + 6291456;     // 1572864
  float* xdbl = ws + 7864320;     // 1572864
  float* dte  = ws + 9437184;     // 6291456
  float* ysb  = ws + 15728640;    // 6291456 (scanC->ln)
  float* SbH0 = xx;               // 3145728 = [xx][yln]: Sb(scanA)->H0(scanB)->read(scanC)
  float* Pb   = ysb;              // 3145728, front of ysb (dead until scanC)
  unsigned short* xcb  = (unsigned short*)(ysb + 3145728); // 1572864 bf16 (conv->xdbl)
  unsigned short* xcTb = xcb + 1572864;                    // 1572864 bf16
  unsigned short* Wf   = (unsigned short*)(ysb + 4718592 + 786432); // 294912 bf16 (->xdbl)

  k_cast_w   <<<72,              256, 0, stream>>>(W_xp, Wf);
  k_gemm_in  <<<dim3(128, 6),    256, 0, stream>>>(x, W_in, b_in, xx, zs);
  k_conv     <<<6144,            256, 0, stream>>>(xx, conv_w, conv_b, xc, xcT, xcb, xcTb);
  k_gemm_xdbl<<<dim3(64, 2, 2),  256, 0, stream>>>(xcb, xcTb, Wf, b_xp, xdbl);
  k_gemm_dt  <<<dim3(64, 12, 2), 256, 0, stream>>>(xdbl, W_dt, b_dt, dt_bias, dte);
  k_scanA    <<<768,             256, 0, stream>>>(xc, xcT, xdbl, dte, A_log, Pb, SbH0);
  k_scanB    <<<96,              256, 0, stream>>>(Pb, SbH0);
  k_scanC    <<<768,             256, 0, stream>>>(xc, xcT, xdbl, dte, A_log, D_skip, SbH0, ysb);
  k_ln       <<<2048,            256, 0, stream>>>(ysb, zs, gamma, beta, yln);
  k_gemm_out <<<dim3(128, 2),    256, 0, stream>>>(yln, W_out, b_out, out);
}